// Round 3
// baseline (1089.549 us; speedup 1.0000x reference)
//
#include <hip/hip_runtime.h>

// VQ-VAE vector quantization, MI355X.
// z_e: (8,64,64,64) f32 (B,D,H,W); emb: (8192,64) f32.
// N = 32768 rows (n = b*4096 + h*64 + w), D = 64, K = 8192.
// out (f32, flat concat): z_q[2097152] | indices[32768] | loss | perplexity | usage
//
// The grading reference is a literal numpy (float32) translation:
//   a2 = np.sum(zf*zf,1) [pairwise-8]; b2 likewise; ab = sgemm;
//   dist = (a2 - 2*ab) + b2 (elementwise fp32); np.argmin (first occurrence).
// Distances sit at magnitude a2~64 -> quantized to ulp(64)=7.6e-6; exact argmin
// differs from the reference on quantization-tie rows. So: fast fp32 top-2 pass
// flags rows with gap < 1e-3, then a re-rank pass reproduces numpy's fp32
// rounding (pairwise-8 a2/b2, fp64-exact ab rounded to fp32, single-rounded
// adds) for flagged rows only.

#define K_CODES   8192
#define DIMV      64
#define IDX_OFF   2097152
#define SCAL_OFF  2129920
#define MARGIN    1e-3f     // quantization reorder is <=~1.5e-5; 65x headroom

// workspace layout (bytes)
#define WS_B2    0          // 8192 f32  (numpy-emulated |e|^2)
#define WS_IDX   32768      // 32768 i32
#define WS_CNT   163840     // 8192 i32
#define WS_LOSS  196608     // 1 f32 (+pad)
#define WS_FLAG  196672     // 32768 i32
#define WS_A2    327744     // 32768 f32 (numpy-emulated |z|^2)

// ---- numpy pairwise-8 emulation helpers (strictly rounded, no contraction) --
__device__ __forceinline__ float pairwise8_sq(const float* __restrict__ x) {
    // sum_{d<64} fl32(x[d]^2) with numpy's 8-accumulator pairwise scheme
    float r[8];
#pragma unroll
    for (int j = 0; j < 8; ++j) r[j] = __fmul_rn(x[j], x[j]);
#pragma unroll
    for (int i = 8; i < 64; i += 8)
#pragma unroll
        for (int j = 0; j < 8; ++j)
            r[j] = __fadd_rn(r[j], __fmul_rn(x[i + j], x[i + j]));
    const float s01 = __fadd_rn(r[0], r[1]);
    const float s23 = __fadd_rn(r[2], r[3]);
    const float s45 = __fadd_rn(r[4], r[5]);
    const float s67 = __fadd_rn(r[6], r[7]);
    return __fadd_rn(__fadd_rn(s01, s23), __fadd_rn(s45, s67));
}

// |e_k|^2, numpy scheme. One thread per code.
__global__ __launch_bounds__(256)
void vq_b2np_kernel(const float* __restrict__ emb, float* __restrict__ b2) {
    const int k = blockIdx.x * 256 + threadIdx.x;
    if (k >= K_CODES) return;
    float v[64];
    const float4* row = (const float4*)(emb + k * DIMV);
#pragma unroll
    for (int i = 0; i < 16; ++i) {
        const float4 q = row[i];
        v[i * 4 + 0] = q.x; v[i * 4 + 1] = q.y; v[i * 4 + 2] = q.z; v[i * 4 + 3] = q.w;
    }
    b2[k] = pairwise8_sq(v);
}

// |z_n|^2, numpy scheme. One block per (b,h); lane w owns row n. Coalesced.
__global__ __launch_bounds__(64)
void vq_a2np_kernel(const float* __restrict__ z_e, float* __restrict__ a2) {
    const int tile = blockIdx.x;            // 0..511
    const int b = tile >> 6, h = tile & 63, w = threadIdx.x;
    const float* base = z_e + (b << 18) + (h << 6) + w;  // + d*4096 per element
    float v[64];
#pragma unroll
    for (int d = 0; d < 64; ++d) v[d] = base[d << 12];
    a2[tile * 64 + w] = pairwise8_sq(v);
}

// Fast fp32 ranking pass (score = b2 - 2 z.e): top-2 + flag.
__global__ __launch_bounds__(256)
void vq_argmin_kernel(const float* __restrict__ z_e, const float* __restrict__ emb,
                      const float* __restrict__ b2, int* __restrict__ idx_out,
                      int* __restrict__ flags) {
    __shared__ float zs[64][68];
    __shared__ float es[128][66];

    const int tid = threadIdx.x;
    const int cg  = tid & 31;
    const int rg  = tid >> 5;
    const int tile = blockIdx.x;
    const int b = tile >> 6;
    const int h = tile & 63;

    {
        const int w  = tid & 63;
        const int dq = tid >> 6;
#pragma unroll
        for (int i = 0; i < 16; ++i) {
            const int dd = dq + i * 4;
            zs[w][dd] = z_e[((b * 64 + dd) << 12) + (h << 6) + w];
        }
    }

    float b1v[8], b2v[8];
    int   b1i[8];
#pragma unroll
    for (int i = 0; i < 8; ++i) { b1v[i] = 3.4e38f; b2v[i] = 3.4e38f; b1i[i] = 0; }

    const int cl  = tid >> 4;
    const int dq4 = (tid & 15) * 4;

    for (int kt = 0; kt < K_CODES; kt += 128) {
        __syncthreads();
#pragma unroll
        for (int p = 0; p < 8; ++p) {
            const int c = p * 16 + cl;
            const float4 v = *(const float4*)(emb + (kt + c) * DIMV + dq4);
            float2* dst = (float2*)&es[c][dq4];
            dst[0] = make_float2(v.x, v.y);
            dst[1] = make_float2(v.z, v.w);
        }
        float bb[4];
#pragma unroll
        for (int j = 0; j < 4; ++j) bb[j] = b2[kt + j * 32 + cg];
        __syncthreads();

        float acc[8][4];
#pragma unroll
        for (int i = 0; i < 8; ++i)
#pragma unroll
            for (int j = 0; j < 4; ++j) acc[i][j] = 0.f;

        for (int d0 = 0; d0 < DIMV; d0 += 4) {
            float4 zr[8];
#pragma unroll
            for (int i = 0; i < 8; ++i) zr[i] = *(const float4*)&zs[rg * 8 + i][d0];
#pragma unroll
            for (int dd = 0; dd < 4; ++dd) {
                float ev[4];
#pragma unroll
                for (int j = 0; j < 4; ++j) ev[j] = es[j * 32 + cg][d0 + dd];
#pragma unroll
                for (int i = 0; i < 8; ++i) {
                    const float zv = (dd == 0) ? zr[i].x : (dd == 1) ? zr[i].y
                                   : (dd == 2) ? zr[i].z : zr[i].w;
#pragma unroll
                    for (int j = 0; j < 4; ++j) acc[i][j] = fmaf(zv, ev[j], acc[i][j]);
                }
            }
        }
#pragma unroll
        for (int i = 0; i < 8; ++i)
#pragma unroll
            for (int j = 0; j < 4; ++j) {
                const float dist = bb[j] - 2.0f * acc[i][j];
                if (dist < b1v[i]) { b2v[i] = b1v[i]; b1v[i] = dist; b1i[i] = kt + j * 32 + cg; }
                else               { b2v[i] = fminf(b2v[i], dist); }
            }
    }

#pragma unroll
    for (int m = 16; m >= 1; m >>= 1) {
#pragma unroll
        for (int i = 0; i < 8; ++i) {
            const float ov1 = __shfl_xor(b1v[i], m);
            const int   oi1 = __shfl_xor(b1i[i], m);
            const float ov2 = __shfl_xor(b2v[i], m);
            const bool take = (ov1 < b1v[i]) || (ov1 == b1v[i] && oi1 < b1i[i]);
            const float nb2 = take ? fminf(b1v[i], ov2) : fminf(b2v[i], ov1);
            if (take) { b1v[i] = ov1; b1i[i] = oi1; }
            b2v[i] = nb2;
        }
    }
    if (cg == 0) {
#pragma unroll
        for (int i = 0; i < 8; ++i) {
            const int n = tile * 64 + rg * 8 + i;
            idx_out[n] = b1i[i];
            flags[n]   = (b2v[i] - b1v[i] < MARGIN) ? 1 : 0;
        }
    }
}

// numpy-fp32-emulated re-rank over all K for flagged rows.
__global__ __launch_bounds__(256)
void vq_refine_np_kernel(const float* __restrict__ z_e, const float* __restrict__ emb,
                         const float* __restrict__ a2, const float* __restrict__ b2,
                         const int* __restrict__ flags, int* __restrict__ idx_out) {
    const int n = blockIdx.x;
    if (flags[n] == 0) return;
    const int tid = threadIdx.x;
    const int b = n >> 12, h = (n >> 6) & 63, w = n & 63;

    __shared__ float zsh[64];
    if (tid < 64) zsh[tid] = z_e[(((b << 6) + tid) << 12) + (h << 6) + w];
    __syncthreads();

    const float a2n = a2[n];
    float best = 3.4e38f;
    int   bi   = 0;
    for (int k = tid; k < K_CODES; k += 256) {      // per-thread k ascending
        const float4* er = (const float4*)(emb + k * DIMV);
        double s = 0.0;
#pragma unroll
        for (int i = 0; i < 16; ++i) {
            const float4 e4 = er[i];
            s += (double)zsh[i * 4 + 0] * (double)e4.x;
            s += (double)zsh[i * 4 + 1] * (double)e4.y;
            s += (double)zsh[i * 4 + 2] * (double)e4.z;
            s += (double)zsh[i * 4 + 3] * (double)e4.w;
        }
        const float qab  = (float)s;                 // fp32-rounded exact dot (sgemm proxy)
        const float m2ab = __fmul_rn(-2.0f, qab);    // exact (x2 power of two)
        const float t1   = __fadd_rn(a2n, m2ab);     // fl32(a2 - 2ab)
        const float dist = __fadd_rn(t1, b2[k]);     // fl32(t1 + b2)
        if (dist < best) { best = dist; bi = k; }
    }

    __shared__ float bv[256];
    __shared__ int   bix[256];
    bv[tid] = best; bix[tid] = bi;
    __syncthreads();
#pragma unroll
    for (int s = 128; s > 0; s >>= 1) {
        if (tid < s) {
            const float ov = bv[tid + s];
            const int   oi = bix[tid + s];
            if (ov < bv[tid] || (ov == bv[tid] && oi < bix[tid])) { bv[tid] = ov; bix[tid] = oi; }
        }
        __syncthreads();
    }
    if (tid == 0) idx_out[n] = bix[0];
}

// z_q gather + commit-loss partial + counts + indices-as-float
__global__ __launch_bounds__(256)
void vq_quant_kernel(const float* __restrict__ z_e, const float* __restrict__ emb,
                     const int* __restrict__ idx, float* __restrict__ out,
                     int* __restrict__ counts, float* __restrict__ loss_acc) {
    const int t  = blockIdx.x * 256 + threadIdx.x;
    const int f0 = t * 4;
    const int w0 = f0 & 63;
    const int h  = (f0 >> 6) & 63;
    const int d  = (f0 >> 12) & 63;
    const int b  = f0 >> 18;
    const int nb = (b << 12) + (h << 6) + w0;

    const float4 z = *(const float4*)(z_e + f0);
    const int i0 = idx[nb], i1 = idx[nb + 1], i2 = idx[nb + 2], i3 = idx[nb + 3];
    float4 q;
    q.x = emb[i0 * DIMV + d];
    q.y = emb[i1 * DIMV + d];
    q.z = emb[i2 * DIMV + d];
    q.w = emb[i3 * DIMV + d];
    *(float4*)(out + f0) = q;

    const float dx = z.x - q.x, dy = z.y - q.y, dz = z.z - q.z, dw = z.w - q.w;
    float dl = dx * dx + dy * dy + dz * dz + dw * dw;

    if (d == 0) {
        out[IDX_OFF + nb + 0] = (float)i0;
        out[IDX_OFF + nb + 1] = (float)i1;
        out[IDX_OFF + nb + 2] = (float)i2;
        out[IDX_OFF + nb + 3] = (float)i3;
        atomicAdd(&counts[i0], 1);
        atomicAdd(&counts[i1], 1);
        atomicAdd(&counts[i2], 1);
        atomicAdd(&counts[i3], 1);
    }

    __shared__ float red[256];
    red[threadIdx.x] = dl;
    __syncthreads();
#pragma unroll
    for (int s = 128; s > 0; s >>= 1) {
        if (threadIdx.x < s) red[threadIdx.x] += red[threadIdx.x + s];
        __syncthreads();
    }
    if (threadIdx.x == 0) atomicAdd(loss_acc, red[0]);
}

__global__ __launch_bounds__(256)
void vq_stats_kernel(const int* __restrict__ counts, const float* __restrict__ loss_acc,
                     float* __restrict__ out) {
    __shared__ float rent[256];
    __shared__ float ruse[256];
    float ent = 0.f, used = 0.f;
    for (int k = threadIdx.x; k < K_CODES; k += 256) {
        const int c = counts[k];
        if (c > 0) {
            const float avg = (float)c * (1.0f / 32768.0f);
            ent  += avg * logf(avg + 1e-10f);
            used += 1.0f;
        }
    }
    rent[threadIdx.x] = ent;
    ruse[threadIdx.x] = used;
    __syncthreads();
#pragma unroll
    for (int s = 128; s > 0; s >>= 1) {
        if (threadIdx.x < s) {
            rent[threadIdx.x] += rent[threadIdx.x + s];
            ruse[threadIdx.x] += ruse[threadIdx.x + s];
        }
        __syncthreads();
    }
    if (threadIdx.x == 0) {
        out[SCAL_OFF + 0] = 0.25f * loss_acc[0] * (1.0f / 2097152.0f);
        out[SCAL_OFF + 1] = expf(-rent[0]);
        out[SCAL_OFF + 2] = ruse[0] * (1.0f / 8192.0f);
    }
}

extern "C" void kernel_launch(void* const* d_in, const int* in_sizes, int n_in,
                              void* d_out, int out_size, void* d_ws, size_t ws_size,
                              hipStream_t stream) {
    const float* z_e = (const float*)d_in[0];
    const float* emb = (const float*)d_in[1];
    float* out = (float*)d_out;
    char*  ws  = (char*)d_ws;

    float* b2     = (float*)(ws + WS_B2);
    int*   idx    = (int*)(ws + WS_IDX);
    int*   counts = (int*)(ws + WS_CNT);
    float* loss   = (float*)(ws + WS_LOSS);
    int*   flags  = (int*)(ws + WS_FLAG);
    float* a2     = (float*)(ws + WS_A2);

    hipMemsetAsync(ws + WS_CNT, 0, 32768 + 16, stream);

    hipLaunchKernelGGL(vq_b2np_kernel,     dim3(32),    dim3(256), 0, stream, emb, b2);
    hipLaunchKernelGGL(vq_a2np_kernel,     dim3(512),   dim3(64),  0, stream, z_e, a2);
    hipLaunchKernelGGL(vq_argmin_kernel,   dim3(512),   dim3(256), 0, stream, z_e, emb, b2, idx, flags);
    hipLaunchKernelGGL(vq_refine_np_kernel,dim3(32768), dim3(256), 0, stream, z_e, emb, a2, b2, flags, idx);
    hipLaunchKernelGGL(vq_quant_kernel,    dim3(2048),  dim3(256), 0, stream, z_e, emb, idx, out, counts, loss);
    hipLaunchKernelGGL(vq_stats_kernel,    dim3(1),     dim3(256), 0, stream, counts, loss, out);
}

// Round 4
// 766.886 us; speedup vs baseline: 1.4207x; 1.4207x over previous
//
#include <hip/hip_runtime.h>

// VQ-VAE vector quantization, MI355X (gfx950).
// z_e: (8,64,64,64) f32 (B,D,H,W); emb: (8192,64) f32.
// N = 32768 rows (n = b*4096 + h*64 + w), D = 64, K = 8192.
// out (f32 concat): z_q[2097152] | indices[32768] | loss | perplexity | usage
//
// Fast pass: split-bf16 MFMA (z_hi*e_hi + z_hi*e_lo + z_lo*e_hi), score error
// ~1e-6. Rows whose fast top1/top2 gap < MARGIN get a numpy-fp32-emulated
// re-rank (pairwise-8 a2/b2, fp64 dot as sgemm proxy, single-rounded adds) —
// this matched the np reference exactly in round 3.

#define K_CODES   8192
#define DIMV      64
#define IDX_OFF   2097152
#define SCAL_OFF  2129920
#define MARGIN    3e-4f   // flip bound ~2e-5 (np rounding dominates); 15x headroom

// workspace layout (bytes)
#define WS_B2    0              // 8192 f32
#define WS_IDX   32768          // 32768 i32
#define WS_CNT   163840         // 8192 i32
#define WS_LOSS  196608         // 1 f32 (+pad)
#define WS_FLAG  196672         // 32768 i32
#define WS_A2    327744         // 32768 f32
#define WS_EHI   458816         // 8192*64 bf16 (1 MB)
#define WS_ELO   1507392        // 1 MB
#define WS_ZHI   2555968        // 32768*64 bf16 (4 MB)
#define WS_ZLO   6750272        // 4 MB
#define WS_P1V   10944576       // 2*32768 f32
#define WS_P2V   11206720       // 2*32768 f32
#define WS_P1I   11468864       // 2*32768 i32  (ends 11731008)

typedef short s16x8  __attribute__((ext_vector_type(8)));
typedef float f32x4  __attribute__((ext_vector_type(4)));

__device__ __forceinline__ short bf16rne(float x) {
    unsigned u = __float_as_uint(x);
    unsigned r = (u + 0x7FFFu + ((u >> 16) & 1u)) >> 16;
    return (short)r;
}
__device__ __forceinline__ float bf16tof(short s) {
    return __uint_as_float(((unsigned)(unsigned short)s) << 16);
}

// numpy pairwise-8 sum of squares (strictly rounded, no contraction)
__device__ __forceinline__ float pairwise8_sq(const float* __restrict__ x) {
    float r[8];
#pragma unroll
    for (int j = 0; j < 8; ++j) r[j] = __fmul_rn(x[j], x[j]);
#pragma unroll
    for (int i = 8; i < 64; i += 8)
#pragma unroll
        for (int j = 0; j < 8; ++j)
            r[j] = __fadd_rn(r[j], __fmul_rn(x[i + j], x[i + j]));
    const float s01 = __fadd_rn(r[0], r[1]);
    const float s23 = __fadd_rn(r[2], r[3]);
    const float s45 = __fadd_rn(r[4], r[5]);
    const float s67 = __fadd_rn(r[6], r[7]);
    return __fadd_rn(__fadd_rn(s01, s23), __fadd_rn(s45, s67));
}

// emb -> b2 (numpy-exact) + bf16 hi/lo split. One thread per code.
__global__ __launch_bounds__(256)
void vq_prep_emb(const float* __restrict__ emb, float* __restrict__ b2,
                 short* __restrict__ e_hi, short* __restrict__ e_lo) {
    const int k = blockIdx.x * 256 + threadIdx.x;
    if (k >= K_CODES) return;
    float v[64];
    const float4* row = (const float4*)(emb + k * DIMV);
#pragma unroll
    for (int i = 0; i < 16; ++i) {
        const float4 q = row[i];
        v[i*4+0] = q.x; v[i*4+1] = q.y; v[i*4+2] = q.z; v[i*4+3] = q.w;
    }
    b2[k] = pairwise8_sq(v);
    s16x8 h[8], l[8];
#pragma unroll
    for (int i = 0; i < 64; ++i) {
        const short hh = bf16rne(v[i]);
        ((short*)h)[i] = hh;
        ((short*)l)[i] = bf16rne(v[i] - bf16tof(hh));
    }
#pragma unroll
    for (int i = 0; i < 8; ++i) {
        *(s16x8*)(e_hi + k * DIMV + i * 8) = h[i];
        *(s16x8*)(e_lo + k * DIMV + i * 8) = l[i];
    }
}

// z_e -> transposed [n][d] bf16 hi/lo + a2 (numpy-exact). Block per (b,h).
__global__ __launch_bounds__(256)
void vq_prep_z(const float* __restrict__ z_e, float* __restrict__ a2,
               short* __restrict__ zt_hi, short* __restrict__ zt_lo) {
    __shared__ float zs[64][65];
    const int tid = threadIdx.x;
    const int tile = blockIdx.x;          // 0..511
    const int b = tile >> 6, h = tile & 63;
    {
        const int w = tid & 63, dq = tid >> 6;
#pragma unroll
        for (int i = 0; i < 16; ++i) {
            const int dd = dq + i * 4;
            zs[w][dd] = z_e[((b * 64 + dd) << 12) + (h << 6) + w];
        }
    }
    __syncthreads();
    if (tid < 64) {
        float v[64];
#pragma unroll
        for (int d = 0; d < 64; ++d) v[d] = zs[tid][d];
        a2[tile * 64 + tid] = pairwise8_sq(v);
    }
    const int w = tid & 63, dq = tid >> 6;        // dq: 16-d chunk
    const int n = tile * 64 + w;
    s16x8 h8[2], l8[2];
#pragma unroll
    for (int i = 0; i < 16; ++i) {
        const float x = zs[w][dq * 16 + i];
        const short hh = bf16rne(x);
        ((short*)h8)[i] = hh;
        ((short*)l8)[i] = bf16rne(x - bf16tof(hh));
    }
    *(s16x8*)(zt_hi + n * DIMV + dq * 16)     = h8[0];
    *(s16x8*)(zt_hi + n * DIMV + dq * 16 + 8) = h8[1];
    *(s16x8*)(zt_lo + n * DIMV + dq * 16)     = l8[0];
    *(s16x8*)(zt_lo + n * DIMV + dq * 16 + 8) = l8[1];
}

// MFMA fast pass. Grid 1024 = 512 row-tiles x 2 K-halves. 4 waves/block,
// wave = 16 rows; chunk = 64 codes (4 tiles of 16). No LDS; e-frags from L2.
__global__ __launch_bounds__(256, 4)
void vq_argmin_mfma(const short* __restrict__ zt_hi, const short* __restrict__ zt_lo,
                    const short* __restrict__ e_hi, const short* __restrict__ e_lo,
                    const float* __restrict__ b2,
                    float* __restrict__ p_b1v, float* __restrict__ p_b2v,
                    int* __restrict__ p_b1i) {
    const int tid  = threadIdx.x;
    const int lane = tid & 63;
    const int wid  = tid >> 6;
    const int blk  = blockIdx.x;
    const int half = blk & 1;
    const int tile = blk >> 1;
    const int n0   = tile * 64 + wid * 16;

    const int lcol = lane & 15;         // C col (code) / A row / B col
    const int koff = (lane >> 4) * 8;   // K slice for A/B frags

    // A frags: z rows n0+lcol, K=64 in two 32-chunks, hi+lo (hoisted).
    const short* za = zt_hi + (size_t)(n0 + lcol) * DIMV + koff;
    const short* zb = zt_lo + (size_t)(n0 + lcol) * DIMV + koff;
    const s16x8 a_h0 = *(const s16x8*)(za);
    const s16x8 a_h1 = *(const s16x8*)(za + 32);
    const s16x8 a_l0 = *(const s16x8*)(zb);
    const s16x8 a_l1 = *(const s16x8*)(zb + 32);

    float b1v[4], b2v[4]; int b1i[4];
#pragma unroll
    for (int r = 0; r < 4; ++r) { b1v[r] = 3.4e38f; b2v[r] = 3.4e38f; b1i[r] = 0; }

    const int kbeg = half * 4096;
    const size_t ebase = (size_t)lcol * DIMV + koff;

    for (int kt = kbeg; kt < kbeg + 4096; kt += 64) {
        const short* ph = e_hi + (size_t)kt * DIMV + ebase;
        const short* pl = e_lo + (size_t)kt * DIMV + ebase;
        s16x8 bh[4][2], bl[4][2];
#pragma unroll
        for (int ct = 0; ct < 4; ++ct) {
            bh[ct][0] = *(const s16x8*)(ph + ct * 1024);
            bh[ct][1] = *(const s16x8*)(ph + ct * 1024 + 32);
            bl[ct][0] = *(const s16x8*)(pl + ct * 1024);
            bl[ct][1] = *(const s16x8*)(pl + ct * 1024 + 32);
        }
        float b2f[4];
#pragma unroll
        for (int ct = 0; ct < 4; ++ct) b2f[ct] = b2[kt + ct * 16 + lcol];

#pragma unroll
        for (int ct = 0; ct < 4; ++ct) {
            f32x4 acc = {0.f, 0.f, 0.f, 0.f};
            acc = __builtin_amdgcn_mfma_f32_16x16x32_bf16(a_h0, bh[ct][0], acc, 0, 0, 0);
            acc = __builtin_amdgcn_mfma_f32_16x16x32_bf16(a_h1, bh[ct][1], acc, 0, 0, 0);
            acc = __builtin_amdgcn_mfma_f32_16x16x32_bf16(a_l0, bh[ct][0], acc, 0, 0, 0);
            acc = __builtin_amdgcn_mfma_f32_16x16x32_bf16(a_l1, bh[ct][1], acc, 0, 0, 0);
            acc = __builtin_amdgcn_mfma_f32_16x16x32_bf16(a_h0, bl[ct][0], acc, 0, 0, 0);
            acc = __builtin_amdgcn_mfma_f32_16x16x32_bf16(a_h1, bl[ct][1], acc, 0, 0, 0);
            const int code = kt + ct * 16 + lcol;
#pragma unroll
            for (int r = 0; r < 4; ++r) {
                const float v = fmaf(-2.0f, acc[r], b2f[ct]);
                if (v < b1v[r]) { b2v[r] = b1v[r]; b1v[r] = v; b1i[r] = code; }
                else             b2v[r] = fminf(b2v[r], v);
            }
        }
    }

    // merge top-2 across the 16 C-columns (xor masks 1..8 keep lane>>4 fixed)
#pragma unroll
    for (int m = 8; m >= 1; m >>= 1) {
#pragma unroll
        for (int r = 0; r < 4; ++r) {
            const float ov1 = __shfl_xor(b1v[r], m);
            const int   oi1 = __shfl_xor(b1i[r], m);
            const float ov2 = __shfl_xor(b2v[r], m);
            const bool take = (ov1 < b1v[r]) || (ov1 == b1v[r] && oi1 < b1i[r]);
            const float nb2 = take ? fminf(b1v[r], ov2) : fminf(b2v[r], ov1);
            if (take) { b1v[r] = ov1; b1i[r] = oi1; }
            b2v[r] = nb2;
        }
    }
    if (lcol == 0) {
#pragma unroll
        for (int r = 0; r < 4; ++r) {
            const int n = n0 + (lane >> 4) * 4 + r;   // C row
            p_b1v[half * 32768 + n] = b1v[r];
            p_b2v[half * 32768 + n] = b2v[r];
            p_b1i[half * 32768 + n] = b1i[r];
        }
    }
}

// merge the two K-half partials -> idx + flags
__global__ __launch_bounds__(256)
void vq_merge(const float* __restrict__ p_b1v, const float* __restrict__ p_b2v,
              const int* __restrict__ p_b1i, int* __restrict__ idx_out,
              int* __restrict__ flags) {
    const int n = blockIdx.x * 256 + threadIdx.x;
    const float v0 = p_b1v[n], v1 = p_b1v[32768 + n];
    const float s0 = p_b2v[n], s1 = p_b2v[32768 + n];
    const int   i0 = p_b1i[n], i1 = p_b1i[32768 + n];
    // half0 indices < half1 indices -> tie keeps half0
    const bool take1 = (v1 < v0);
    const float b1 = take1 ? v1 : v0;
    const int   bi = take1 ? i1 : i0;
    const float bsec = take1 ? fminf(v0, s1) : fminf(s0, v1);
    idx_out[n] = bi;
    flags[n]   = (bsec - b1 < MARGIN) ? 1 : 0;
}

// numpy-fp32-emulated re-rank over all K for flagged rows (round-3 verified).
__global__ __launch_bounds__(256)
void vq_refine_np_kernel(const float* __restrict__ z_e, const float* __restrict__ emb,
                         const float* __restrict__ a2, const float* __restrict__ b2,
                         const int* __restrict__ flags, int* __restrict__ idx_out) {
    const int n = blockIdx.x;
    if (flags[n] == 0) return;
    const int tid = threadIdx.x;
    const int b = n >> 12, h = (n >> 6) & 63, w = n & 63;

    __shared__ float zsh[64];
    if (tid < 64) zsh[tid] = z_e[(((b << 6) + tid) << 12) + (h << 6) + w];
    __syncthreads();

    const float a2n = a2[n];
    float best = 3.4e38f;
    int   bi   = 0;
    for (int k = tid; k < K_CODES; k += 256) {
        const float4* er = (const float4*)(emb + k * DIMV);
        double s = 0.0;
#pragma unroll
        for (int i = 0; i < 16; ++i) {
            const float4 e4 = er[i];
            s += (double)zsh[i*4+0] * (double)e4.x;
            s += (double)zsh[i*4+1] * (double)e4.y;
            s += (double)zsh[i*4+2] * (double)e4.z;
            s += (double)zsh[i*4+3] * (double)e4.w;
        }
        const float qab  = (float)s;
        const float m2ab = __fmul_rn(-2.0f, qab);
        const float t1   = __fadd_rn(a2n, m2ab);
        const float dist = __fadd_rn(t1, b2[k]);
        if (dist < best) { best = dist; bi = k; }
    }

    __shared__ float bv[256];
    __shared__ int   bix[256];
    bv[tid] = best; bix[tid] = bi;
    __syncthreads();
#pragma unroll
    for (int s = 128; s > 0; s >>= 1) {
        if (tid < s) {
            const float ov = bv[tid + s];
            const int   oi = bix[tid + s];
            if (ov < bv[tid] || (ov == bv[tid] && oi < bix[tid])) { bv[tid] = ov; bix[tid] = oi; }
        }
        __syncthreads();
    }
    if (tid == 0) idx_out[n] = bix[0];
}

// z_q gather + commit-loss partial + counts + indices-as-float
__global__ __launch_bounds__(256)
void vq_quant_kernel(const float* __restrict__ z_e, const float* __restrict__ emb,
                     const int* __restrict__ idx, float* __restrict__ out,
                     int* __restrict__ counts, float* __restrict__ loss_acc) {
    const int t  = blockIdx.x * 256 + threadIdx.x;
    const int f0 = t * 4;
    const int w0 = f0 & 63;
    const int h  = (f0 >> 6) & 63;
    const int d  = (f0 >> 12) & 63;
    const int b  = f0 >> 18;
    const int nb = (b << 12) + (h << 6) + w0;

    const float4 z = *(const float4*)(z_e + f0);
    const int i0 = idx[nb], i1 = idx[nb+1], i2 = idx[nb+2], i3 = idx[nb+3];
    float4 q;
    q.x = emb[i0 * DIMV + d];
    q.y = emb[i1 * DIMV + d];
    q.z = emb[i2 * DIMV + d];
    q.w = emb[i3 * DIMV + d];
    *(float4*)(out + f0) = q;

    const float dx = z.x - q.x, dy = z.y - q.y, dz = z.z - q.z, dw = z.w - q.w;
    float dl = dx*dx + dy*dy + dz*dz + dw*dw;

    if (d == 0) {
        out[IDX_OFF + nb + 0] = (float)i0;
        out[IDX_OFF + nb + 1] = (float)i1;
        out[IDX_OFF + nb + 2] = (float)i2;
        out[IDX_OFF + nb + 3] = (float)i3;
        atomicAdd(&counts[i0], 1);
        atomicAdd(&counts[i1], 1);
        atomicAdd(&counts[i2], 1);
        atomicAdd(&counts[i3], 1);
    }

    __shared__ float red[256];
    red[threadIdx.x] = dl;
    __syncthreads();
#pragma unroll
    for (int s = 128; s > 0; s >>= 1) {
        if (threadIdx.x < s) red[threadIdx.x] += red[threadIdx.x + s];
        __syncthreads();
    }
    if (threadIdx.x == 0) atomicAdd(loss_acc, red[0]);
}

__global__ __launch_bounds__(256)
void vq_stats_kernel(const int* __restrict__ counts, const float* __restrict__ loss_acc,
                     float* __restrict__ out) {
    __shared__ float rent[256];
    __shared__ float ruse[256];
    float ent = 0.f, used = 0.f;
    for (int k = threadIdx.x; k < K_CODES; k += 256) {
        const int c = counts[k];
        if (c > 0) {
            const float avg = (float)c * (1.0f / 32768.0f);
            ent  += avg * logf(avg + 1e-10f);
            used += 1.0f;
        }
    }
    rent[threadIdx.x] = ent;
    ruse[threadIdx.x] = used;
    __syncthreads();
#pragma unroll
    for (int s = 128; s > 0; s >>= 1) {
        if (threadIdx.x < s) {
            rent[threadIdx.x] += rent[threadIdx.x + s];
            ruse[threadIdx.x] += ruse[threadIdx.x + s];
        }
        __syncthreads();
    }
    if (threadIdx.x == 0) {
        out[SCAL_OFF + 0] = 0.25f * loss_acc[0] * (1.0f / 2097152.0f);
        out[SCAL_OFF + 1] = expf(-rent[0]);
        out[SCAL_OFF + 2] = ruse[0] * (1.0f / 8192.0f);
    }
}

extern "C" void kernel_launch(void* const* d_in, const int* in_sizes, int n_in,
                              void* d_out, int out_size, void* d_ws, size_t ws_size,
                              hipStream_t stream) {
    const float* z_e = (const float*)d_in[0];
    const float* emb = (const float*)d_in[1];
    float* out = (float*)d_out;
    char*  ws  = (char*)d_ws;

    float* b2     = (float*)(ws + WS_B2);
    int*   idx    = (int*)(ws + WS_IDX);
    int*   counts = (int*)(ws + WS_CNT);
    float* loss   = (float*)(ws + WS_LOSS);
    int*   flags  = (int*)(ws + WS_FLAG);
    float* a2     = (float*)(ws + WS_A2);
    short* e_hi   = (short*)(ws + WS_EHI);
    short* e_lo   = (short*)(ws + WS_ELO);
    short* zt_hi  = (short*)(ws + WS_ZHI);
    short* zt_lo  = (short*)(ws + WS_ZLO);
    float* p_b1v  = (float*)(ws + WS_P1V);
    float* p_b2v  = (float*)(ws + WS_P2V);
    int*   p_b1i  = (int*)(ws + WS_P1I);

    hipMemsetAsync(ws + WS_CNT, 0, 32768 + 16, stream);

    hipLaunchKernelGGL(vq_prep_emb,    dim3(32),    dim3(256), 0, stream, emb, b2, e_hi, e_lo);
    hipLaunchKernelGGL(vq_prep_z,      dim3(512),   dim3(256), 0, stream, z_e, a2, zt_hi, zt_lo);
    hipLaunchKernelGGL(vq_argmin_mfma, dim3(1024),  dim3(256), 0, stream,
                       zt_hi, zt_lo, e_hi, e_lo, b2, p_b1v, p_b2v, p_b1i);
    hipLaunchKernelGGL(vq_merge,       dim3(128),   dim3(256), 0, stream,
                       p_b1v, p_b2v, p_b1i, idx, flags);
    hipLaunchKernelGGL(vq_refine_np_kernel, dim3(32768), dim3(256), 0, stream,
                       z_e, emb, a2, b2, flags, idx);
    hipLaunchKernelGGL(vq_quant_kernel, dim3(2048), dim3(256), 0, stream,
                       z_e, emb, idx, out, counts, loss);
    hipLaunchKernelGGL(vq_stats_kernel, dim3(1),    dim3(256), 0, stream, counts, loss, out);
}

// Round 5
// 351.384 us; speedup vs baseline: 3.1007x; 2.1825x over previous
//
#include <hip/hip_runtime.h>

// VQ-VAE vector quantization, MI355X (gfx950).
// z_e: (8,64,64,64) f32 (B,D,H,W); emb: (8192,64) f32.
// N = 32768 rows (n = b*4096 + h*64 + w), D = 64, K = 8192.
// out (f32 concat): z_q[2097152] | indices[32768] | loss | perplexity | usage
//
// Fast pass: split-bf16 MFMA (z_hi*e_hi + z_hi*e_lo + z_lo*e_hi) with e stored
// pre-arranged in MFMA fragment blocks -> LDS staging is a linear copy and all
// ds_read_b128 are contiguous-1KB conflict-free. Double-buffered LDS, 2 row-
// tiles per wave. Rows with fast top1/top2 gap < MARGIN get the numpy-fp32-
// emulated re-rank (round-3-verified) over a COMPACTED flag list.

#define K_CODES   8192
#define DIMV      64
#define IDX_OFF   2097152
#define SCAL_OFF  2129920
#define MARGIN    3e-4f   // split-bf16 score err ~1e-6, np rounding ~2e-5; 15x headroom

// workspace layout (bytes)
#define WS_B2    0              // 8192 f32
#define WS_IDX   32768          // 32768 i32
#define WS_CNT   163840         // 8192 i32  (memset 0)
#define WS_LOSS  196608         // 1 f32     (memset 0)
#define WS_FCNT  196612         // 1 i32     (memset 0)
#define WS_FLIST 196672         // 32768 i32
#define WS_A2    327744         // 32768 f32
#define WS_EFRAG 458816         // 128 chunks * 16 KB = 2 MB (frag-blocked e hi/lo)
#define WS_ZHI   2555968        // 32768*64 bf16 (4 MB)
#define WS_ZLO   6750272        // 4 MB
#define WS_P1V   10944576       // 2*32768 f32
#define WS_P2V   11206720       // 2*32768 f32
#define WS_P1I   11468864       // 2*32768 i32 (ends 11731008)

typedef short s16x8  __attribute__((ext_vector_type(8)));
typedef float f32x4  __attribute__((ext_vector_type(4)));

__device__ __forceinline__ short bf16rne(float x) {
    unsigned u = __float_as_uint(x);
    unsigned r = (u + 0x7FFFu + ((u >> 16) & 1u)) >> 16;
    return (short)r;
}
__device__ __forceinline__ float bf16tof(short s) {
    return __uint_as_float(((unsigned)(unsigned short)s) << 16);
}

// numpy pairwise-8 sum of squares (strictly rounded, no contraction)
__device__ __forceinline__ float pairwise8_sq(const float* __restrict__ x) {
    float r[8];
#pragma unroll
    for (int j = 0; j < 8; ++j) r[j] = __fmul_rn(x[j], x[j]);
#pragma unroll
    for (int i = 8; i < 64; i += 8)
#pragma unroll
        for (int j = 0; j < 8; ++j)
            r[j] = __fadd_rn(r[j], __fmul_rn(x[i + j], x[i + j]));
    const float s01 = __fadd_rn(r[0], r[1]);
    const float s23 = __fadd_rn(r[2], r[3]);
    const float s45 = __fadd_rn(r[4], r[5]);
    const float s67 = __fadd_rn(r[6], r[7]);
    return __fadd_rn(__fadd_rn(s01, s23), __fadd_rn(s45, s67));
}

// emb -> b2 (numpy-exact) + frag-blocked bf16 hi/lo.
// Chunk c = 64 codes. Frag f = ct*4 + s*2 + term (ct=code/16 in chunk, s=K-slice,
// term 0=hi 1=lo). Within frag: lane = (kgroup&3)*16 + (code&15), 8 shorts at
// lane*16 bytes covering k = (kgroup)*8..+8. -> ds_read_b128 at base+lane*16.
__global__ __launch_bounds__(256)
void vq_prep_emb(const float* __restrict__ emb, float* __restrict__ b2,
                 short* __restrict__ efrag) {
    const int k = blockIdx.x * 256 + threadIdx.x;
    if (k >= K_CODES) return;
    float v[64];
    const float4* row = (const float4*)(emb + k * DIMV);
#pragma unroll
    for (int i = 0; i < 16; ++i) {
        const float4 q = row[i];
        v[i*4+0] = q.x; v[i*4+1] = q.y; v[i*4+2] = q.z; v[i*4+3] = q.w;
    }
    b2[k] = pairwise8_sq(v);
    const int c = k >> 6, ct = (k >> 4) & 3, lcol = k & 15;
#pragma unroll
    for (int g = 0; g < 8; ++g) {
        s16x8 hv, lv;
#pragma unroll
        for (int j = 0; j < 8; ++j) {
            const float x = v[g*8 + j];
            const short hh = bf16rne(x);
            hv[j] = hh;
            lv[j] = bf16rne(x - bf16tof(hh));
        }
        const int f  = ct*4 + (g >> 2)*2;
        const int ln = (g & 3)*16 + lcol;
        *(s16x8*)(efrag + c*8192 + f*512       + ln*8) = hv;
        *(s16x8*)(efrag + c*8192 + (f+1)*512   + ln*8) = lv;
    }
}

// z_e -> transposed [n][d] bf16 hi/lo + a2 (numpy-exact). Block per (b,h).
__global__ __launch_bounds__(256)
void vq_prep_z(const float* __restrict__ z_e, float* __restrict__ a2,
               short* __restrict__ zt_hi, short* __restrict__ zt_lo) {
    __shared__ float zs[64][65];
    const int tid = threadIdx.x;
    const int tile = blockIdx.x;          // 0..511
    const int b = tile >> 6, h = tile & 63;
    {
        const int w = tid & 63, dq = tid >> 6;
#pragma unroll
        for (int i = 0; i < 16; ++i) {
            const int dd = dq + i * 4;
            zs[w][dd] = z_e[((b * 64 + dd) << 12) + (h << 6) + w];
        }
    }
    __syncthreads();
    if (tid < 64) {
        float v[64];
#pragma unroll
        for (int d = 0; d < 64; ++d) v[d] = zs[tid][d];
        a2[tile * 64 + tid] = pairwise8_sq(v);
    }
    const int w = tid & 63, dq = tid >> 6;        // dq: 16-d chunk
    const int n = tile * 64 + w;
    s16x8 h8[2], l8[2];
#pragma unroll
    for (int i = 0; i < 16; ++i) {
        const float x = zs[w][dq * 16 + i];
        const short hh = bf16rne(x);
        ((short*)h8)[i] = hh;
        ((short*)l8)[i] = bf16rne(x - bf16tof(hh));
    }
    *(s16x8*)(zt_hi + n * DIMV + dq * 16)     = h8[0];
    *(s16x8*)(zt_hi + n * DIMV + dq * 16 + 8) = h8[1];
    *(s16x8*)(zt_lo + n * DIMV + dq * 16)     = l8[0];
    *(s16x8*)(zt_lo + n * DIMV + dq * 16 + 8) = l8[1];
}

// MFMA fast pass with double-buffered LDS e-tiles.
// Grid 512 = 256 row-groups (128 rows) x 2 K-halves. 4 waves/block; each wave
// owns 32 rows (2x16-row tiles). Chunk = 64 codes (16 KB frag data in LDS).
__global__ __launch_bounds__(256, 2)
void vq_argmin_mfma(const short* __restrict__ zt_hi, const short* __restrict__ zt_lo,
                    const short* __restrict__ efrag, const float* __restrict__ b2,
                    float* __restrict__ p_b1v, float* __restrict__ p_b2v,
                    int* __restrict__ p_b1i) {
    __shared__ __align__(16) char lds[2][16384];
    const int tid  = threadIdx.x;
    const int lane = tid & 63;
    const int wid  = tid >> 6;
    const int blk  = blockIdx.x;
    const int half = blk & 1;
    const int rgrp = blk >> 1;
    const int n0   = rgrp * 128 + wid * 32;
    const int lcol = lane & 15;
    const int kq   = lane >> 4;

    // A frags (hoisted): rows n0 + rt*16 + lcol, k = kq*8 (+32 for slice 1)
    s16x8 a_h[2][2], a_l[2][2];
#pragma unroll
    for (int rt = 0; rt < 2; ++rt) {
        const short* zh = zt_hi + (size_t)(n0 + rt*16 + lcol) * DIMV + kq*8;
        const short* zl = zt_lo + (size_t)(n0 + rt*16 + lcol) * DIMV + kq*8;
        a_h[rt][0] = *(const s16x8*)(zh);
        a_h[rt][1] = *(const s16x8*)(zh + 32);
        a_l[rt][0] = *(const s16x8*)(zl);
        a_l[rt][1] = *(const s16x8*)(zl + 32);
    }

    float b1v[2][4], b2v[2][4]; int b1i[2][4];
#pragma unroll
    for (int rt = 0; rt < 2; ++rt)
#pragma unroll
        for (int r = 0; r < 4; ++r) { b1v[rt][r] = 3.4e38f; b2v[rt][r] = 3.4e38f; b1i[rt][r] = 0; }

    const int c0 = half * 64;                     // chunk range [c0, c0+64)
    const char* gbase = (const char*)efrag;

    // prologue: stage chunk c0 -> lds[0]
    float4 st[4];
#pragma unroll
    for (int i = 0; i < 4; ++i)
        st[i] = *(const float4*)(gbase + (size_t)c0*16384 + i*4096 + tid*16);
#pragma unroll
    for (int i = 0; i < 4; ++i)
        *(float4*)(&lds[0][i*4096 + tid*16]) = st[i];

    for (int t = 0; t < 64; ++t) {
        __syncthreads();                           // lds[t&1] ready; prev reads done
        if (t < 63) {                              // issue next-chunk loads early
#pragma unroll
            for (int i = 0; i < 4; ++i)
                st[i] = *(const float4*)(gbase + (size_t)(c0 + t + 1)*16384 + i*4096 + tid*16);
        }
        const char* base = lds[t & 1];
        s16x8 B[16];
#pragma unroll
        for (int f = 0; f < 16; ++f)
            B[f] = *(const s16x8*)(base + f*1024 + lane*16);

        const int kt = (c0 + t) * 64;
        float b2f[4];
#pragma unroll
        for (int ct = 0; ct < 4; ++ct) b2f[ct] = b2[kt + ct*16 + lcol];

#pragma unroll
        for (int ct = 0; ct < 4; ++ct) {
            const int code = kt + ct*16 + lcol;
#pragma unroll
            for (int rt = 0; rt < 2; ++rt) {
                f32x4 acc = {0.f, 0.f, 0.f, 0.f};
                acc = __builtin_amdgcn_mfma_f32_16x16x32_bf16(a_h[rt][0], B[ct*4+0], acc, 0, 0, 0);
                acc = __builtin_amdgcn_mfma_f32_16x16x32_bf16(a_h[rt][1], B[ct*4+2], acc, 0, 0, 0);
                acc = __builtin_amdgcn_mfma_f32_16x16x32_bf16(a_l[rt][0], B[ct*4+0], acc, 0, 0, 0);
                acc = __builtin_amdgcn_mfma_f32_16x16x32_bf16(a_l[rt][1], B[ct*4+2], acc, 0, 0, 0);
                acc = __builtin_amdgcn_mfma_f32_16x16x32_bf16(a_h[rt][0], B[ct*4+1], acc, 0, 0, 0);
                acc = __builtin_amdgcn_mfma_f32_16x16x32_bf16(a_h[rt][1], B[ct*4+3], acc, 0, 0, 0);
#pragma unroll
                for (int r = 0; r < 4; ++r) {
                    const float v = fmaf(-2.0f, acc[r], b2f[ct]);
                    // top-2: second = med3(v, b1, b2) (see round-5 note), then min
                    const bool lt = (v < b1v[rt][r]);
                    b2v[rt][r] = fminf(fmaxf(v, b1v[rt][r]), b2v[rt][r]);
                    b1i[rt][r] = lt ? code : b1i[rt][r];
                    b1v[rt][r] = fminf(v, b1v[rt][r]);
                }
            }
        }
        if (t < 63) {
#pragma unroll
            for (int i = 0; i < 4; ++i)
                *(float4*)(&lds[(t + 1) & 1][i*4096 + tid*16]) = st[i];
        }
    }

    // merge top-2 across the 16 code-columns (masks <=8 keep kq fixed)
#pragma unroll
    for (int m = 8; m >= 1; m >>= 1) {
#pragma unroll
        for (int rt = 0; rt < 2; ++rt)
#pragma unroll
            for (int r = 0; r < 4; ++r) {
                const float ov1 = __shfl_xor(b1v[rt][r], m);
                const int   oi1 = __shfl_xor(b1i[rt][r], m);
                const float ov2 = __shfl_xor(b2v[rt][r], m);
                const bool take = (ov1 < b1v[rt][r]) || (ov1 == b1v[rt][r] && oi1 < b1i[rt][r]);
                const float nb2 = take ? fminf(b1v[rt][r], ov2) : fminf(b2v[rt][r], ov1);
                if (take) { b1v[rt][r] = ov1; b1i[rt][r] = oi1; }
                b2v[rt][r] = nb2;
            }
    }
    if (lcol == 0) {
#pragma unroll
        for (int rt = 0; rt < 2; ++rt)
#pragma unroll
            for (int r = 0; r < 4; ++r) {
                const int n = n0 + rt*16 + kq*4 + r;
                p_b1v[half * 32768 + n] = b1v[rt][r];
                p_b2v[half * 32768 + n] = b2v[rt][r];
                p_b1i[half * 32768 + n] = b1i[rt][r];
            }
    }
}

// merge K-half partials -> idx + compacted flag list
__global__ __launch_bounds__(256)
void vq_merge(const float* __restrict__ p_b1v, const float* __restrict__ p_b2v,
              const int* __restrict__ p_b1i, int* __restrict__ idx_out,
              int* __restrict__ fcnt, int* __restrict__ flist) {
    const int n = blockIdx.x * 256 + threadIdx.x;
    const float v0 = p_b1v[n], v1 = p_b1v[32768 + n];
    const float s0 = p_b2v[n], s1 = p_b2v[32768 + n];
    const int   i0 = p_b1i[n], i1 = p_b1i[32768 + n];
    const bool take1 = (v1 < v0);                  // half0 wins ties (lower idx)
    const float b1   = take1 ? v1 : v0;
    const int   bi   = take1 ? i1 : i0;
    const float bsec = take1 ? fminf(v0, s1) : fminf(s0, v1);
    idx_out[n] = bi;
    if (bsec - b1 < MARGIN) {
        const int p = atomicAdd(fcnt, 1);
        flist[p] = n;
    }
}

// numpy-fp32-emulated re-rank over all K for flagged rows (round-3-verified
// numerics), grid-striding a compacted list.
__global__ __launch_bounds__(256)
void vq_refine_np(const float* __restrict__ z_e, const float* __restrict__ emb,
                  const float* __restrict__ a2, const float* __restrict__ b2,
                  const int* __restrict__ fcnt, const int* __restrict__ flist,
                  int* __restrict__ idx_out) {
    __shared__ float zsh[64];
    __shared__ float bv[256];
    __shared__ int   bix[256];
    const int tid = threadIdx.x;
    const int cnt = *fcnt;
    for (int it = blockIdx.x; it < cnt; it += gridDim.x) {
        const int n = flist[it];
        const int b = n >> 12, h = (n >> 6) & 63, w = n & 63;
        __syncthreads();
        if (tid < 64) zsh[tid] = z_e[(((b << 6) + tid) << 12) + (h << 6) + w];
        __syncthreads();

        const float a2n = a2[n];
        float best = 3.4e38f;
        int   bi   = 0;
        for (int k = tid; k < K_CODES; k += 256) {
            const float4* er = (const float4*)(emb + k * DIMV);
            double s0 = 0.0, s1 = 0.0, s2 = 0.0, s3 = 0.0;
#pragma unroll
            for (int i = 0; i < 16; ++i) {
                const float4 e4 = er[i];
                s0 += (double)zsh[i*4+0] * (double)e4.x;
                s1 += (double)zsh[i*4+1] * (double)e4.y;
                s2 += (double)zsh[i*4+2] * (double)e4.z;
                s3 += (double)zsh[i*4+3] * (double)e4.w;
            }
            const float qab  = (float)((s0 + s1) + (s2 + s3));  // sgemm proxy
            const float m2ab = __fmul_rn(-2.0f, qab);
            const float t1   = __fadd_rn(a2n, m2ab);
            const float dist = __fadd_rn(t1, b2[k]);
            if (dist < best) { best = dist; bi = k; }
        }
        bv[tid] = best; bix[tid] = bi;
        __syncthreads();
#pragma unroll
        for (int s = 128; s > 0; s >>= 1) {
            if (tid < s) {
                const float ov = bv[tid + s];
                const int   oi = bix[tid + s];
                if (ov < bv[tid] || (ov == bv[tid] && oi < bix[tid])) { bv[tid] = ov; bix[tid] = oi; }
            }
            __syncthreads();
        }
        if (tid == 0) idx_out[n] = bix[0];
    }
}

// z_q gather + commit-loss partial + counts + indices-as-float
__global__ __launch_bounds__(256)
void vq_quant_kernel(const float* __restrict__ z_e, const float* __restrict__ emb,
                     const int* __restrict__ idx, float* __restrict__ out,
                     int* __restrict__ counts, float* __restrict__ loss_acc) {
    const int t  = blockIdx.x * 256 + threadIdx.x;
    const int f0 = t * 4;
    const int w0 = f0 & 63;
    const int h  = (f0 >> 6) & 63;
    const int d  = (f0 >> 12) & 63;
    const int b  = f0 >> 18;
    const int nb = (b << 12) + (h << 6) + w0;

    const float4 z = *(const float4*)(z_e + f0);
    const int i0 = idx[nb], i1 = idx[nb+1], i2 = idx[nb+2], i3 = idx[nb+3];
    float4 q;
    q.x = emb[i0 * DIMV + d];
    q.y = emb[i1 * DIMV + d];
    q.z = emb[i2 * DIMV + d];
    q.w = emb[i3 * DIMV + d];
    *(float4*)(out + f0) = q;

    const float dx = z.x - q.x, dy = z.y - q.y, dz = z.z - q.z, dw = z.w - q.w;
    float dl = dx*dx + dy*dy + dz*dz + dw*dw;

    if (d == 0) {
        out[IDX_OFF + nb + 0] = (float)i0;
        out[IDX_OFF + nb + 1] = (float)i1;
        out[IDX_OFF + nb + 2] = (float)i2;
        out[IDX_OFF + nb + 3] = (float)i3;
        atomicAdd(&counts[i0], 1);
        atomicAdd(&counts[i1], 1);
        atomicAdd(&counts[i2], 1);
        atomicAdd(&counts[i3], 1);
    }

    __shared__ float red[256];
    red[threadIdx.x] = dl;
    __syncthreads();
#pragma unroll
    for (int s = 128; s > 0; s >>= 1) {
        if (threadIdx.x < s) red[threadIdx.x] += red[threadIdx.x + s];
        __syncthreads();
    }
    if (threadIdx.x == 0) atomicAdd(loss_acc, red[0]);
}

__global__ __launch_bounds__(256)
void vq_stats_kernel(const int* __restrict__ counts, const float* __restrict__ loss_acc,
                     float* __restrict__ out) {
    __shared__ float rent[256];
    __shared__ float ruse[256];
    float ent = 0.f, used = 0.f;
    for (int k = threadIdx.x; k < K_CODES; k += 256) {
        const int c = counts[k];
        if (c > 0) {
            const float avg = (float)c * (1.0f / 32768.0f);
            ent  += avg * logf(avg + 1e-10f);
            used += 1.0f;
        }
    }
    rent[threadIdx.x] = ent;
    ruse[threadIdx.x] = used;
    __syncthreads();
#pragma unroll
    for (int s = 128; s > 0; s >>= 1) {
        if (threadIdx.x < s) {
            rent[threadIdx.x] += rent[threadIdx.x + s];
            ruse[threadIdx.x] += ruse[threadIdx.x + s];
        }
        __syncthreads();
    }
    if (threadIdx.x == 0) {
        out[SCAL_OFF + 0] = 0.25f * loss_acc[0] * (1.0f / 2097152.0f);
        out[SCAL_OFF + 1] = expf(-rent[0]);
        out[SCAL_OFF + 2] = ruse[0] * (1.0f / 8192.0f);
    }
}

extern "C" void kernel_launch(void* const* d_in, const int* in_sizes, int n_in,
                              void* d_out, int out_size, void* d_ws, size_t ws_size,
                              hipStream_t stream) {
    const float* z_e = (const float*)d_in[0];
    const float* emb = (const float*)d_in[1];
    float* out = (float*)d_out;
    char*  ws  = (char*)d_ws;

    float* b2     = (float*)(ws + WS_B2);
    int*   idx    = (int*)(ws + WS_IDX);
    int*   counts = (int*)(ws + WS_CNT);
    float* loss   = (float*)(ws + WS_LOSS);
    int*   fcnt   = (int*)(ws + WS_FCNT);
    int*   flist  = (int*)(ws + WS_FLIST);
    float* a2     = (float*)(ws + WS_A2);
    short* efrag  = (short*)(ws + WS_EFRAG);
    short* zt_hi  = (short*)(ws + WS_ZHI);
    short* zt_lo  = (short*)(ws + WS_ZLO);
    float* p_b1v  = (float*)(ws + WS_P1V);
    float* p_b2v  = (float*)(ws + WS_P2V);
    int*   p_b1i  = (int*)(ws + WS_P1I);

    // zero counts + loss + fcnt (contiguous)
    hipMemsetAsync(ws + WS_CNT, 0, 32768 + 64, stream);

    hipLaunchKernelGGL(vq_prep_emb,    dim3(32),   dim3(256), 0, stream, emb, b2, efrag);
    hipLaunchKernelGGL(vq_prep_z,      dim3(512),  dim3(256), 0, stream, z_e, a2, zt_hi, zt_lo);
    hipLaunchKernelGGL(vq_argmin_mfma, dim3(512),  dim3(256), 0, stream,
                       zt_hi, zt_lo, efrag, b2, p_b1v, p_b2v, p_b1i);
    hipLaunchKernelGGL(vq_merge,       dim3(128),  dim3(256), 0, stream,
                       p_b1v, p_b2v, p_b1i, idx, fcnt, flist);
    hipLaunchKernelGGL(vq_refine_np,   dim3(1024), dim3(256), 0, stream,
                       z_e, emb, a2, b2, fcnt, flist, idx);
    hipLaunchKernelGGL(vq_quant_kernel, dim3(2048), dim3(256), 0, stream,
                       z_e, emb, idx, out, counts, loss);
    hipLaunchKernelGGL(vq_stats_kernel, dim3(1),    dim3(256), 0, stream, counts, loss, out);
}

// Round 8
// 344.564 us; speedup vs baseline: 3.1621x; 1.0198x over previous
//
#include <hip/hip_runtime.h>

// VQ-VAE vector quantization, MI355X (gfx950).
// z_e: (8,64,64,64) f32 (B,D,H,W); emb: (8192,64) f32.
// N = 32768 rows (n = b*4096 + h*64 + w), D = 64, K = 8192.
// out (f32 concat): z_q[2097152] | indices[32768] | loss | perplexity | usage
//
// Fast pass: split-bf16 MFMA of score = b2 + z.(-2e). e is stored pre-scaled
// by -2 (exact) and pre-arranged in MFMA fragment blocks; acc is initialized
// with b2 (per-lane column constant) so NO epilogue FMA is needed. Rows with
// fast top1/top2 gap < MARGIN get the numpy-fp32-emulated re-rank
// (round-3-verified) over a compacted flag list.

#define K_CODES   8192
#define DIMV      64
#define IDX_OFF   2097152
#define SCAL_OFF  2129920
#define MARGIN    3e-4f   // fast-score err ~2e-6, np rounding ~2e-5; 15x headroom

// workspace layout (bytes)
#define WS_B2    0              // 8192 f32
#define WS_IDX   32768          // 32768 i32
#define WS_CNT   163840         // 8192 i32  (memset 0)
#define WS_LOSS  196608         // 1 f32     (memset 0)
#define WS_FCNT  196612         // 1 i32     (memset 0)
#define WS_FLIST 196672         // 32768 i32
#define WS_A2    327744         // 32768 f32
#define WS_EFRAG 458816         // 128 chunks * 16 KB = 2 MB (frag-blocked -2e hi/lo)
#define WS_ZHI   2555968        // 32768*64 bf16 (4 MB)
#define WS_ZLO   6750272        // 4 MB
#define WS_P1V   10944576       // 4*32768 f32
#define WS_P2V   11468864       // 4*32768 f32
#define WS_P1I   11993152       // 4*32768 i32 (ends 12517440)

typedef short s16x8  __attribute__((ext_vector_type(8)));
typedef float f32x4  __attribute__((ext_vector_type(4)));

__device__ __forceinline__ short bf16rne(float x) {
    unsigned u = __float_as_uint(x);
    unsigned r = (u + 0x7FFFu + ((u >> 16) & 1u)) >> 16;
    return (short)r;
}
__device__ __forceinline__ float bf16tof(short s) {
    return __uint_as_float(((unsigned)(unsigned short)s) << 16);
}

// numpy pairwise-8 sum of squares (strictly rounded, no contraction)
__device__ __forceinline__ float pairwise8_sq(const float* __restrict__ x) {
    float r[8];
#pragma unroll
    for (int j = 0; j < 8; ++j) r[j] = __fmul_rn(x[j], x[j]);
#pragma unroll
    for (int i = 8; i < 64; i += 8)
#pragma unroll
        for (int j = 0; j < 8; ++j)
            r[j] = __fadd_rn(r[j], __fmul_rn(x[i + j], x[i + j]));
    const float s01 = __fadd_rn(r[0], r[1]);
    const float s23 = __fadd_rn(r[2], r[3]);
    const float s45 = __fadd_rn(r[4], r[5]);
    const float s67 = __fadd_rn(r[6], r[7]);
    return __fadd_rn(__fadd_rn(s01, s23), __fadd_rn(s45, s67));
}

// emb -> b2 (numpy-exact) + frag-blocked bf16 hi/lo of (-2e).
// Chunk c = 64 codes; frag f = ct*4 + slice*2 + term; within frag lane
// (kgroup&3)*16 + (code&15) holds 8 shorts at lane*16 B.
__global__ __launch_bounds__(128)
void vq_prep_emb(const float* __restrict__ emb, float* __restrict__ b2,
                 short* __restrict__ efrag) {
    const int k = blockIdx.x * 128 + threadIdx.x;
    if (k >= K_CODES) return;
    float v[64];
    const float4* row = (const float4*)(emb + k * DIMV);
#pragma unroll
    for (int i = 0; i < 16; ++i) {
        const float4 q = row[i];
        v[i*4+0] = q.x; v[i*4+1] = q.y; v[i*4+2] = q.z; v[i*4+3] = q.w;
    }
    b2[k] = pairwise8_sq(v);
    const int c = k >> 6, ct = (k >> 4) & 3, lcol = k & 15;
#pragma unroll
    for (int g = 0; g < 8; ++g) {
        s16x8 hv, lv;
#pragma unroll
        for (int j = 0; j < 8; ++j) {
            const float x = -2.0f * v[g*8 + j];          // exact scale
            const short hh = bf16rne(x);
            hv[j] = hh;
            lv[j] = bf16rne(x - bf16tof(hh));
        }
        const int f  = ct*4 + (g >> 2)*2;
        const int ln = (g & 3)*16 + lcol;
        *(s16x8*)(efrag + c*8192 + f*512     + ln*8) = hv;
        *(s16x8*)(efrag + c*8192 + (f+1)*512 + ln*8) = lv;
    }
}

// z_e -> transposed [n][d] bf16 hi/lo + a2 (numpy-exact). Block per (b,h).
__global__ __launch_bounds__(256)
void vq_prep_z(const float* __restrict__ z_e, float* __restrict__ a2,
               short* __restrict__ zt_hi, short* __restrict__ zt_lo) {
    __shared__ float zs[64][65];
    const int tid = threadIdx.x;
    const int tile = blockIdx.x;          // 0..511
    const int b = tile >> 6, h = tile & 63;
    {
        const int w = tid & 63, dq = tid >> 6;
#pragma unroll
        for (int i = 0; i < 16; ++i) {
            const int dd = dq + i * 4;
            zs[w][dd] = z_e[((b * 64 + dd) << 12) + (h << 6) + w];
        }
    }
    __syncthreads();
    if (tid < 64) {
        float v[64];
#pragma unroll
        for (int d = 0; d < 64; ++d) v[d] = zs[tid][d];
        a2[tile * 64 + tid] = pairwise8_sq(v);
    }
    const int w = tid & 63, dq = tid >> 6;        // dq: 16-d chunk
    const int n = tile * 64 + w;
    s16x8 h8[2], l8[2];
#pragma unroll
    for (int i = 0; i < 16; ++i) {
        const float x = zs[w][dq * 16 + i];
        const short hh = bf16rne(x);
        ((short*)h8)[i] = hh;
        ((short*)l8)[i] = bf16rne(x - bf16tof(hh));
    }
    *(s16x8*)(zt_hi + n * DIMV + dq * 16)     = h8[0];
    *(s16x8*)(zt_hi + n * DIMV + dq * 16 + 8) = h8[1];
    *(s16x8*)(zt_lo + n * DIMV + dq * 16)     = l8[0];
    *(s16x8*)(zt_lo + n * DIMV + dq * 16 + 8) = l8[1];
}

// MFMA fast pass, double-buffered LDS, 4-way K-split for occupancy.
// Grid 1024 = 256 row-groups (128 rows) x 4 K-quarters. 4 waves/block;
// wave owns 32 rows (2x16). Chunk = 64 codes (16 KB frags in LDS).
__global__ __launch_bounds__(256, 4)
void vq_argmin_mfma(const short* __restrict__ zt_hi, const short* __restrict__ zt_lo,
                    const short* __restrict__ efrag, const float* __restrict__ b2,
                    float* __restrict__ p_b1v, float* __restrict__ p_b2v,
                    int* __restrict__ p_b1i) {
    __shared__ __align__(16) char lds[2][16384];
    const int tid  = threadIdx.x;
    const int lane = tid & 63;
    const int wid  = tid >> 6;
    const int blk  = blockIdx.x;
    const int quar = blk & 3;
    const int rgrp = blk >> 2;
    const int n0   = rgrp * 128 + wid * 32;
    const int lcol = lane & 15;
    const int kq   = lane >> 4;

    // A frags (hoisted): rows n0 + rt*16 + lcol, k slices kq*8 / +32
    s16x8 a_h[2][2], a_l[2][2];
#pragma unroll
    for (int rt = 0; rt < 2; ++rt) {
        const short* zh = zt_hi + (size_t)(n0 + rt*16 + lcol) * DIMV + kq*8;
        const short* zl = zt_lo + (size_t)(n0 + rt*16 + lcol) * DIMV + kq*8;
        a_h[rt][0] = *(const s16x8*)(zh);
        a_h[rt][1] = *(const s16x8*)(zh + 32);
        a_l[rt][0] = *(const s16x8*)(zl);
        a_l[rt][1] = *(const s16x8*)(zl + 32);
    }

    float b1v[2][4], b2v[2][4]; int b1i[2][4];
#pragma unroll
    for (int rt = 0; rt < 2; ++rt)
#pragma unroll
        for (int r = 0; r < 4; ++r) { b1v[rt][r] = 3.4e38f; b2v[rt][r] = 3.4e38f; b1i[rt][r] = 0; }

    const int c0 = quar * 32;                     // chunk range [c0, c0+32)
    const char* gbase = (const char*)efrag;

    // prologue: stage chunk c0 -> lds[0]
    float4 st[4];
#pragma unroll
    for (int i = 0; i < 4; ++i)
        st[i] = *(const float4*)(gbase + (size_t)c0*16384 + i*4096 + tid*16);
#pragma unroll
    for (int i = 0; i < 4; ++i)
        *(float4*)(&lds[0][i*4096 + tid*16]) = st[i];

    for (int t = 0; t < 32; ++t) {
        __syncthreads();                           // lds[t&1] ready; prev reads done
        if (t < 31) {                              // issue next-chunk loads early
#pragma unroll
            for (int i = 0; i < 4; ++i)
                st[i] = *(const float4*)(gbase + (size_t)(c0 + t + 1)*16384 + i*4096 + tid*16);
        }
        const char* base = lds[t & 1];
        s16x8 B[16];
#pragma unroll
        for (int f = 0; f < 16; ++f)
            B[f] = *(const s16x8*)(base + f*1024 + lane*16);

        const int kt = (c0 + t) * 64;
        float b2f[4];
#pragma unroll
        for (int ct = 0; ct < 4; ++ct) b2f[ct] = b2[kt + ct*16 + lcol];

#pragma unroll
        for (int ct = 0; ct < 4; ++ct) {
            const int code = kt + ct*16 + lcol;
#pragma unroll
            for (int rt = 0; rt < 2; ++rt) {
                // acc init = b2 (all 4 C-regs of a lane share column `code`)
                f32x4 acc = {b2f[ct], b2f[ct], b2f[ct], b2f[ct]};
                acc = __builtin_amdgcn_mfma_f32_16x16x32_bf16(a_h[rt][0], B[ct*4+0], acc, 0, 0, 0);
                acc = __builtin_amdgcn_mfma_f32_16x16x32_bf16(a_h[rt][1], B[ct*4+2], acc, 0, 0, 0);
                acc = __builtin_amdgcn_mfma_f32_16x16x32_bf16(a_l[rt][0], B[ct*4+0], acc, 0, 0, 0);
                acc = __builtin_amdgcn_mfma_f32_16x16x32_bf16(a_l[rt][1], B[ct*4+2], acc, 0, 0, 0);
                acc = __builtin_amdgcn_mfma_f32_16x16x32_bf16(a_h[rt][0], B[ct*4+1], acc, 0, 0, 0);
                acc = __builtin_amdgcn_mfma_f32_16x16x32_bf16(a_h[rt][1], B[ct*4+3], acc, 0, 0, 0);
#pragma unroll
                for (int r = 0; r < 4; ++r) {
                    const float v = acc[r];        // score = b2 - 2 z.e
                    const bool lt = (v < b1v[rt][r]);
                    b2v[rt][r] = fminf(fmaxf(v, b1v[rt][r]), b2v[rt][r]);
                    b1i[rt][r] = lt ? code : b1i[rt][r];
                    b1v[rt][r] = fminf(v, b1v[rt][r]);
                }
            }
        }
        if (t < 31) {
#pragma unroll
            for (int i = 0; i < 4; ++i)
                *(float4*)(&lds[(t + 1) & 1][i*4096 + tid*16]) = st[i];
        }
    }

    // merge top-2 across the 16 code-columns (masks <=8 keep kq fixed)
#pragma unroll
    for (int m = 8; m >= 1; m >>= 1) {
#pragma unroll
        for (int rt = 0; rt < 2; ++rt)
#pragma unroll
            for (int r = 0; r < 4; ++r) {
                const float ov1 = __shfl_xor(b1v[rt][r], m);
                const int   oi1 = __shfl_xor(b1i[rt][r], m);
                const float ov2 = __shfl_xor(b2v[rt][r], m);
                const bool take = (ov1 < b1v[rt][r]) || (ov1 == b1v[rt][r] && oi1 < b1i[rt][r]);
                const float nb2 = take ? fminf(b1v[rt][r], ov2) : fminf(b2v[rt][r], ov1);
                if (take) { b1v[rt][r] = ov1; b1i[rt][r] = oi1; }
                b2v[rt][r] = nb2;
            }
    }
    if (lcol == 0) {
#pragma unroll
        for (int rt = 0; rt < 2; ++rt)
#pragma unroll
            for (int r = 0; r < 4; ++r) {
                const int n = n0 + rt*16 + kq*4 + r;
                p_b1v[quar * 32768 + n] = b1v[rt][r];
                p_b2v[quar * 32768 + n] = b2v[rt][r];
                p_b1i[quar * 32768 + n] = b1i[rt][r];
            }
    }
}

// merge 4 K-quarter partials -> idx + idx-as-float + counts + compacted flags
__global__ __launch_bounds__(256)
void vq_merge(const float* __restrict__ p_b1v, const float* __restrict__ p_b2v,
              const int* __restrict__ p_b1i, int* __restrict__ idx_out,
              float* __restrict__ out, int* __restrict__ counts,
              int* __restrict__ fcnt, int* __restrict__ flist) {
    const int n = blockIdx.x * 256 + threadIdx.x;
    float b1 = p_b1v[n], sec = p_b2v[n];
    int   bi = p_b1i[n];
#pragma unroll
    for (int q = 1; q < 4; ++q) {
        const float v = p_b1v[q * 32768 + n];
        const float s = p_b2v[q * 32768 + n];
        const int   i = p_b1i[q * 32768 + n];
        const bool take = (v < b1);                // earlier quarter wins ties
        sec = take ? fminf(b1, s) : fminf(sec, v);
        b1  = take ? v : b1;
        bi  = take ? i : bi;
    }
    idx_out[n] = bi;
    out[IDX_OFF + n] = (float)bi;
    atomicAdd(&counts[bi], 1);
    if (sec - b1 < MARGIN) {
        const int p = atomicAdd(fcnt, 1);
        flist[p] = n;
    }
}

// numpy-fp32-emulated re-rank over all K for flagged rows; fixes idx/counts.
__global__ __launch_bounds__(256)
void vq_refine_np(const float* __restrict__ z_e, const float* __restrict__ emb,
                  const float* __restrict__ a2, const float* __restrict__ b2,
                  const int* __restrict__ fcnt, const int* __restrict__ flist,
                  int* __restrict__ idx_out, float* __restrict__ out,
                  int* __restrict__ counts) {
    __shared__ float zsh[64];
    __shared__ float bv[256];
    __shared__ int   bix[256];
    const int tid = threadIdx.x;
    const int cnt = *fcnt;
    for (int it = blockIdx.x; it < cnt; it += gridDim.x) {
        const int n = flist[it];
        const int b = n >> 12, h = (n >> 6) & 63, w = n & 63;
        __syncthreads();
        if (tid < 64) zsh[tid] = z_e[(((b << 6) + tid) << 12) + (h << 6) + w];
        __syncthreads();

        const float a2n = a2[n];
        float best = 3.4e38f;
        int   bi   = 0;
        for (int k = tid; k < K_CODES; k += 256) {
            const float4* er = (const float4*)(emb + k * DIMV);
            double s0 = 0.0, s1 = 0.0, s2 = 0.0, s3 = 0.0;
#pragma unroll
            for (int i = 0; i < 16; ++i) {
                const float4 e4 = er[i];
                s0 += (double)zsh[i*4+0] * (double)e4.x;
                s1 += (double)zsh[i*4+1] * (double)e4.y;
                s2 += (double)zsh[i*4+2] * (double)e4.z;
                s3 += (double)zsh[i*4+3] * (double)e4.w;
            }
            const float qab  = (float)((s0 + s1) + (s2 + s3));  // sgemm proxy
            const float m2ab = __fmul_rn(-2.0f, qab);
            const float t1   = __fadd_rn(a2n, m2ab);
            const float dist = __fadd_rn(t1, b2[k]);
            if (dist < best) { best = dist; bi = k; }
        }
        bv[tid] = best; bix[tid] = bi;
        __syncthreads();
#pragma unroll
        for (int s = 128; s > 0; s >>= 1) {
            if (tid < s) {
                const float ov = bv[tid + s];
                const int   oi = bix[tid + s];
                if (ov < bv[tid] || (ov == bv[tid] && oi < bix[tid])) { bv[tid] = ov; bix[tid] = oi; }
            }
            __syncthreads();
        }
        if (tid == 0) {
            const int newbi = bix[0];
            const int oldbi = idx_out[n];
            if (newbi != oldbi) {
                idx_out[n] = newbi;
                out[IDX_OFF + n] = (float)newbi;
                atomicSub(&counts[oldbi], 1);
                atomicAdd(&counts[newbi], 1);
            }
        }
    }
}

// z_q gather + commit-loss partial
__global__ __launch_bounds__(256)
void vq_quant_kernel(const float* __restrict__ z_e, const float* __restrict__ emb,
                     const int* __restrict__ idx, float* __restrict__ out,
                     float* __restrict__ loss_acc) {
    const int t  = blockIdx.x * 256 + threadIdx.x;
    const int f0 = t * 4;
    const int w0 = f0 & 63;
    const int h  = (f0 >> 6) & 63;
    const int d  = (f0 >> 12) & 63;
    const int b  = f0 >> 18;
    const int nb = (b << 12) + (h << 6) + w0;

    const float4 z = *(const float4*)(z_e + f0);
    const int i0 = idx[nb], i1 = idx[nb+1], i2 = idx[nb+2], i3 = idx[nb+3];
    float4 q;
    q.x = emb[i0 * DIMV + d];
    q.y = emb[i1 * DIMV + d];
    q.z = emb[i2 * DIMV + d];
    q.w = emb[i3 * DIMV + d];
    *(float4*)(out + f0) = q;

    const float dx = z.x - q.x, dy = z.y - q.y, dz = z.z - q.z, dw = z.w - q.w;
    float dl = dx*dx + dy*dy + dz*dz + dw*dw;

    __shared__ float red[256];
    red[threadIdx.x] = dl;
    __syncthreads();
#pragma unroll
    for (int s = 128; s > 0; s >>= 1) {
        if (threadIdx.x < s) red[threadIdx.x] += red[threadIdx.x + s];
        __syncthreads();
    }
    if (threadIdx.x == 0) atomicAdd(loss_acc, red[0]);
}

__global__ __launch_bounds__(256)
void vq_stats_kernel(const int* __restrict__ counts, const float* __restrict__ loss_acc,
                     float* __restrict__ out) {
    __shared__ float rent[256];
    __shared__ float ruse[256];
    float ent = 0.f, used = 0.f;
    for (int k = threadIdx.x; k < K_CODES; k += 256) {
        const int c = counts[k];
        if (c > 0) {
            const float avg = (float)c * (1.0f / 32768.0f);
            ent  += avg * logf(avg + 1e-10f);
            used += 1.0f;
        }
    }
    rent[threadIdx.x] = ent;
    ruse[threadIdx.x] = used;
    __syncthreads();
#pragma unroll
    for (int s = 128; s > 0; s >>= 1) {
        if (threadIdx.x < s) {
            rent[threadIdx.x] += rent[threadIdx.x + s];
            ruse[threadIdx.x] += ruse[threadIdx.x + s];
        }
        __syncthreads();
    }
    if (threadIdx.x == 0) {
        out[SCAL_OFF + 0] = 0.25f * loss_acc[0] * (1.0f / 2097152.0f);
        out[SCAL_OFF + 1] = expf(-rent[0]);
        out[SCAL_OFF + 2] = ruse[0] * (1.0f / 8192.0f);
    }
}

extern "C" void kernel_launch(void* const* d_in, const int* in_sizes, int n_in,
                              void* d_out, int out_size, void* d_ws, size_t ws_size,
                              hipStream_t stream) {
    const float* z_e = (const float*)d_in[0];
    const float* emb = (const float*)d_in[1];
    float* out = (float*)d_out;
    char*  ws  = (char*)d_ws;

    float* b2     = (float*)(ws + WS_B2);
    int*   idx    = (int*)(ws + WS_IDX);
    int*   counts = (int*)(ws + WS_CNT);
    float* loss   = (float*)(ws + WS_LOSS);
    int*   fcnt   = (int*)(ws + WS_FCNT);
    int*   flist  = (int*)(ws + WS_FLIST);
    float* a2     = (float*)(ws + WS_A2);
    short* efrag  = (short*)(ws + WS_EFRAG);
    short* zt_hi  = (short*)(ws + WS_ZHI);
    short* zt_lo  = (short*)(ws + WS_ZLO);
    float* p_b1v  = (float*)(ws + WS_P1V);
    float* p_b2v  = (float*)(ws + WS_P2V);
    int*   p_b1i  = (int*)(ws + WS_P1I);

    // zero counts + loss + fcnt (contiguous, ends exactly at WS_FLIST)
    hipMemsetAsync(ws + WS_CNT, 0, 32768 + 64, stream);

    hipLaunchKernelGGL(vq_prep_emb,    dim3(64),   dim3(128), 0, stream, emb, b2, efrag);
    hipLaunchKernelGGL(vq_prep_z,      dim3(512),  dim3(256), 0, stream, z_e, a2, zt_hi, zt_lo);
    hipLaunchKernelGGL(vq_argmin_mfma, dim3(1024), dim3(256), 0, stream,
                       zt_hi, zt_lo, efrag, b2, p_b1v, p_b2v, p_b1i);
    hipLaunchKernelGGL(vq_merge,       dim3(128),  dim3(256), 0, stream,
                       p_b1v, p_b2v, p_b1i, idx, out, counts, fcnt, flist);
    hipLaunchKernelGGL(vq_refine_np,   dim3(1024), dim3(256), 0, stream,
                       z_e, emb, a2, b2, fcnt, flist, idx, out, counts);
    hipLaunchKernelGGL(vq_quant_kernel, dim3(2048), dim3(256), 0, stream,
                       z_e, emb, idx, out, loss);
    hipLaunchKernelGGL(vq_stats_kernel, dim3(1),    dim3(256), 0, stream, counts, loss, out);
}

// Round 9
// 312.609 us; speedup vs baseline: 3.4853x; 1.1022x over previous
//
#include <hip/hip_runtime.h>

// VQ-VAE vector quantization, MI355X (gfx950).
// z_e: (8,64,64,64) f32 (B,D,H,W); emb: (8192,64) f32.
// N = 32768 rows (n = b*4096 + h*64 + w), D = 64, K = 8192.
// out (f32 concat): z_q[2097152] | indices[32768] | loss | perplexity | usage
//
// Fast pass: split-bf16 MFMA of score = b2 + z.(-2e), e pre-scaled by -2 and
// pre-arranged in MFMA fragment blocks; LDS staged via async global_load_lds
// (width 16); top-2 bookkeeping via v_med3_f32. Rows with fast gap < MARGIN
// get the numpy-fp32-emulated re-rank (round-3-verified).

#define K_CODES   8192
#define DIMV      64
#define IDX_OFF   2097152
#define SCAL_OFF  2129920
#define MARGIN    3e-4f   // fast-score err ~2e-6, np rounding ~2e-5; 15x headroom

// workspace layout (bytes)
#define WS_B2    0              // 8192 f32
#define WS_IDX   32768          // 32768 i32
#define WS_CNT   163840         // 8192 i32  (zeroed in prep)
#define WS_LOSS  196608         // 1 f32     (zeroed in prep)
#define WS_FCNT  196612         // 1 i32     (zeroed in prep)
#define WS_FLIST 196672         // 32768 i32
#define WS_A2    327744         // 32768 f32
#define WS_EFRAG 458816         // 128 chunks * 16 KB = 2 MB (frag-blocked -2e hi/lo)
#define WS_ZHI   2555968        // 32768*64 bf16 (4 MB)
#define WS_ZLO   6750272        // 4 MB
#define WS_P1V   10944576       // 4*32768 f32
#define WS_P2V   11468864       // 4*32768 f32
#define WS_P1I   11993152       // 4*32768 i32 (ends 12517440)

typedef short s16x8  __attribute__((ext_vector_type(8)));
typedef float f32x4  __attribute__((ext_vector_type(4)));

__device__ __forceinline__ short bf16rne(float x) {
    unsigned u = __float_as_uint(x);
    unsigned r = (u + 0x7FFFu + ((u >> 16) & 1u)) >> 16;
    return (short)r;
}
__device__ __forceinline__ float bf16tof(short s) {
    return __uint_as_float(((unsigned)(unsigned short)s) << 16);
}

// async global->LDS copy, 16 B per lane (lds dest = wave-uniform base + lane*16)
__device__ __forceinline__ void gl_lds16(const char* g, char* l) {
    __builtin_amdgcn_global_load_lds(
        (const __attribute__((address_space(1))) unsigned int*)g,
        (__attribute__((address_space(3))) unsigned int*)l, 16, 0, 0);
}

// numpy pairwise-8 sum of squares (strictly rounded, no contraction)
__device__ __forceinline__ float pairwise8_sq(const float* __restrict__ x) {
    float r[8];
#pragma unroll
    for (int j = 0; j < 8; ++j) r[j] = __fmul_rn(x[j], x[j]);
#pragma unroll
    for (int i = 8; i < 64; i += 8)
#pragma unroll
        for (int j = 0; j < 8; ++j)
            r[j] = __fadd_rn(r[j], __fmul_rn(x[i + j], x[i + j]));
    const float s01 = __fadd_rn(r[0], r[1]);
    const float s23 = __fadd_rn(r[2], r[3]);
    const float s45 = __fadd_rn(r[4], r[5]);
    const float s67 = __fadd_rn(r[6], r[7]);
    return __fadd_rn(__fadd_rn(s01, s23), __fadd_rn(s45, s67));
}

// Fused prep: blocks [0,512) do z-prep (one (b,h) tile each); blocks [512,576)
// do emb-prep (128 codes each, tid<128) + zero counts/loss/fcnt.
__global__ __launch_bounds__(256)
void vq_prep(const float* __restrict__ z_e, const float* __restrict__ emb,
             float* __restrict__ a2, float* __restrict__ b2,
             short* __restrict__ zt_hi, short* __restrict__ zt_lo,
             short* __restrict__ efrag, int* __restrict__ zero_base) {
    const int blk = blockIdx.x;
    const int tid = threadIdx.x;
    if (blk < 512) {
        __shared__ float zs[64][65];
        const int b = blk >> 6, h = blk & 63;
        {
            const int w = tid & 63, dq = tid >> 6;
#pragma unroll
            for (int i = 0; i < 16; ++i) {
                const int dd = dq + i * 4;
                zs[w][dd] = z_e[((b * 64 + dd) << 12) + (h << 6) + w];
            }
        }
        __syncthreads();
        if (tid < 64) {
            float v[64];
#pragma unroll
            for (int d = 0; d < 64; ++d) v[d] = zs[tid][d];
            a2[blk * 64 + tid] = pairwise8_sq(v);
        }
        const int w = tid & 63, dq = tid >> 6;
        const int n = blk * 64 + w;
        s16x8 h8[2], l8[2];
#pragma unroll
        for (int i = 0; i < 16; ++i) {
            const float x = zs[w][dq * 16 + i];
            const short hh = bf16rne(x);
            ((short*)h8)[i] = hh;
            ((short*)l8)[i] = bf16rne(x - bf16tof(hh));
        }
        *(s16x8*)(zt_hi + n * DIMV + dq * 16)     = h8[0];
        *(s16x8*)(zt_hi + n * DIMV + dq * 16 + 8) = h8[1];
        *(s16x8*)(zt_lo + n * DIMV + dq * 16)     = l8[0];
        *(s16x8*)(zt_lo + n * DIMV + dq * 16 + 8) = l8[1];
    } else {
        // zero counts[8192] + loss + fcnt (8194 contiguous words at zero_base)
        const int zi = (blk - 512) * 256 + tid;
        if (zi < 8194) zero_base[zi] = 0;
        if (tid < 128) {
            const int k = (blk - 512) * 128 + tid;
            float v[64];
            const float4* row = (const float4*)(emb + k * DIMV);
#pragma unroll
            for (int i = 0; i < 16; ++i) {
                const float4 q = row[i];
                v[i*4+0] = q.x; v[i*4+1] = q.y; v[i*4+2] = q.z; v[i*4+3] = q.w;
            }
            b2[k] = pairwise8_sq(v);
            const int c = k >> 6, ct = (k >> 4) & 3, lcol = k & 15;
#pragma unroll
            for (int g = 0; g < 8; ++g) {
                s16x8 hv, lv;
#pragma unroll
                for (int j = 0; j < 8; ++j) {
                    const float x = -2.0f * v[g*8 + j];      // exact scale
                    const short hh = bf16rne(x);
                    hv[j] = hh;
                    lv[j] = bf16rne(x - bf16tof(hh));
                }
                const int f  = ct*4 + (g >> 2)*2;
                const int ln = (g & 3)*16 + lcol;
                *(s16x8*)(efrag + c*8192 + f*512     + ln*8) = hv;
                *(s16x8*)(efrag + c*8192 + (f+1)*512 + ln*8) = lv;
            }
        }
    }
}

// MFMA fast pass: async-LDS double buffer, med3 top-2, 4-way K-split.
// Grid 1024 = 256 row-groups (128 rows) x 4 K-quarters; 4 waves/block;
// wave owns 32 rows (2x16). Chunk = 64 codes (16 KB frags).
__global__ __launch_bounds__(256, 4)
void vq_argmin_mfma(const short* __restrict__ zt_hi, const short* __restrict__ zt_lo,
                    const short* __restrict__ efrag, const float* __restrict__ b2,
                    float* __restrict__ p_b1v, float* __restrict__ p_b2v,
                    int* __restrict__ p_b1i) {
    __shared__ __align__(16) char lds[2][16384];
    const int tid  = threadIdx.x;
    const int lane = tid & 63;
    const int wid  = tid >> 6;
    const int blk  = blockIdx.x;
    const int quar = blk & 3;
    const int rgrp = blk >> 2;
    const int n0   = rgrp * 128 + wid * 32;
    const int lcol = lane & 15;
    const int kq   = lane >> 4;

    s16x8 a_h[2][2], a_l[2][2];
#pragma unroll
    for (int rt = 0; rt < 2; ++rt) {
        const short* zh = zt_hi + (size_t)(n0 + rt*16 + lcol) * DIMV + kq*8;
        const short* zl = zt_lo + (size_t)(n0 + rt*16 + lcol) * DIMV + kq*8;
        a_h[rt][0] = *(const s16x8*)(zh);
        a_h[rt][1] = *(const s16x8*)(zh + 32);
        a_l[rt][0] = *(const s16x8*)(zl);
        a_l[rt][1] = *(const s16x8*)(zl + 32);
    }

    float b1v[2][4], b2v[2][4]; int b1i[2][4];
#pragma unroll
    for (int rt = 0; rt < 2; ++rt)
#pragma unroll
        for (int r = 0; r < 4; ++r) { b1v[rt][r] = 3.4e38f; b2v[rt][r] = 3.4e38f; b1i[rt][r] = 0; }

    const int c0 = quar * 32;
    const char* gbase = (const char*)efrag;

    // prologue: async-stage chunk c0 -> lds[0]
    {
        const char* src = gbase + (size_t)c0 * 16384 + tid * 16;
        char* dst = &lds[0][tid * 16];
#pragma unroll
        for (int i = 0; i < 4; ++i) gl_lds16(src + i * 4096, dst + i * 4096);
    }

    for (int t = 0; t < 32; ++t) {
        __syncthreads();                           // drains vmcnt: lds[t&1] ready
        if (t < 31) {                              // async-issue next chunk
            const char* src = gbase + (size_t)(c0 + t + 1) * 16384 + tid * 16;
            char* dst = &lds[(t + 1) & 1][tid * 16];
#pragma unroll
            for (int i = 0; i < 4; ++i) gl_lds16(src + i * 4096, dst + i * 4096);
        }
        const char* base = lds[t & 1];
        s16x8 B[16];
#pragma unroll
        for (int f = 0; f < 16; ++f)
            B[f] = *(const s16x8*)(base + f*1024 + lane*16);

        const int kt = (c0 + t) * 64;
        float b2f[4];
#pragma unroll
        for (int ct = 0; ct < 4; ++ct) b2f[ct] = b2[kt + ct*16 + lcol];

#pragma unroll
        for (int ct = 0; ct < 4; ++ct) {
            const int code = kt + ct*16 + lcol;
#pragma unroll
            for (int rt = 0; rt < 2; ++rt) {
                f32x4 acc = {b2f[ct], b2f[ct], b2f[ct], b2f[ct]};
                acc = __builtin_amdgcn_mfma_f32_16x16x32_bf16(a_h[rt][0], B[ct*4+0], acc, 0, 0, 0);
                acc = __builtin_amdgcn_mfma_f32_16x16x32_bf16(a_h[rt][1], B[ct*4+2], acc, 0, 0, 0);
                acc = __builtin_amdgcn_mfma_f32_16x16x32_bf16(a_l[rt][0], B[ct*4+0], acc, 0, 0, 0);
                acc = __builtin_amdgcn_mfma_f32_16x16x32_bf16(a_l[rt][1], B[ct*4+2], acc, 0, 0, 0);
                acc = __builtin_amdgcn_mfma_f32_16x16x32_bf16(a_h[rt][0], B[ct*4+1], acc, 0, 0, 0);
                acc = __builtin_amdgcn_mfma_f32_16x16x32_bf16(a_h[rt][1], B[ct*4+3], acc, 0, 0, 0);
#pragma unroll
                for (int r = 0; r < 4; ++r) {
                    const float v = acc[r];        // score = b2 - 2 z.e
                    // b2 = min(b2, max(v, b1_old)) == med3(v, b1_old, b2)  [b1<=b2]
                    b2v[rt][r] = __builtin_amdgcn_fmed3f(v, b1v[rt][r], b2v[rt][r]);
                    const bool lt = (v < b1v[rt][r]);
                    b1i[rt][r] = lt ? code : b1i[rt][r];
                    b1v[rt][r] = fminf(v, b1v[rt][r]);
                }
            }
        }
    }

    // merge top-2 across the 16 code-columns (masks <=8 keep kq fixed)
#pragma unroll
    for (int m = 8; m >= 1; m >>= 1) {
#pragma unroll
        for (int rt = 0; rt < 2; ++rt)
#pragma unroll
            for (int r = 0; r < 4; ++r) {
                const float ov1 = __shfl_xor(b1v[rt][r], m);
                const int   oi1 = __shfl_xor(b1i[rt][r], m);
                const float ov2 = __shfl_xor(b2v[rt][r], m);
                const bool take = (ov1 < b1v[rt][r]) || (ov1 == b1v[rt][r] && oi1 < b1i[rt][r]);
                const float nb2 = take ? fminf(b1v[rt][r], ov2) : fminf(b2v[rt][r], ov1);
                if (take) { b1v[rt][r] = ov1; b1i[rt][r] = oi1; }
                b2v[rt][r] = nb2;
            }
    }
    if (lcol == 0) {
#pragma unroll
        for (int rt = 0; rt < 2; ++rt)
#pragma unroll
            for (int r = 0; r < 4; ++r) {
                const int n = n0 + rt*16 + kq*4 + r;
                p_b1v[quar * 32768 + n] = b1v[rt][r];
                p_b2v[quar * 32768 + n] = b2v[rt][r];
                p_b1i[quar * 32768 + n] = b1i[rt][r];
            }
    }
}

// merge 4 K-quarter partials -> idx + idx-as-float + counts + compacted flags
__global__ __launch_bounds__(256)
void vq_merge(const float* __restrict__ p_b1v, const float* __restrict__ p_b2v,
              const int* __restrict__ p_b1i, int* __restrict__ idx_out,
              float* __restrict__ out, int* __restrict__ counts,
              int* __restrict__ fcnt, int* __restrict__ flist) {
    const int n = blockIdx.x * 256 + threadIdx.x;
    float b1 = p_b1v[n], sec = p_b2v[n];
    int   bi = p_b1i[n];
#pragma unroll
    for (int q = 1; q < 4; ++q) {
        const float v = p_b1v[q * 32768 + n];
        const float s = p_b2v[q * 32768 + n];
        const int   i = p_b1i[q * 32768 + n];
        const bool take = (v < b1);                // earlier quarter wins ties
        sec = take ? fminf(b1, s) : fminf(sec, v);
        b1  = take ? v : b1;
        bi  = take ? i : bi;
    }
    idx_out[n] = bi;
    out[IDX_OFF + n] = (float)bi;
    atomicAdd(&counts[bi], 1);
    if (sec - b1 < MARGIN) {
        const int p = atomicAdd(fcnt, 1);
        flist[p] = n;
    }
}

// numpy-fp32-emulated re-rank over all K for flagged rows; fixes idx/counts.
__global__ __launch_bounds__(256)
void vq_refine_np(const float* __restrict__ z_e, const float* __restrict__ emb,
                  const float* __restrict__ a2, const float* __restrict__ b2,
                  const int* __restrict__ fcnt, const int* __restrict__ flist,
                  int* __restrict__ idx_out, float* __restrict__ out,
                  int* __restrict__ counts) {
    __shared__ float zsh[64];
    __shared__ float bv[256];
    __shared__ int   bix[256];
    const int tid = threadIdx.x;
    const int cnt = *fcnt;
    for (int it = blockIdx.x; it < cnt; it += gridDim.x) {
        const int n = flist[it];
        const int b = n >> 12, h = (n >> 6) & 63, w = n & 63;
        __syncthreads();
        if (tid < 64) zsh[tid] = z_e[(((b << 6) + tid) << 12) + (h << 6) + w];
        __syncthreads();

        const float a2n = a2[n];
        float best = 3.4e38f;
        int   bi   = 0;
        for (int k = tid; k < K_CODES; k += 256) {
            const float4* er = (const float4*)(emb + k * DIMV);
            double s0 = 0.0, s1 = 0.0, s2 = 0.0, s3 = 0.0;
#pragma unroll
            for (int i = 0; i < 16; ++i) {
                const float4 e4 = er[i];
                s0 += (double)zsh[i*4+0] * (double)e4.x;
                s1 += (double)zsh[i*4+1] * (double)e4.y;
                s2 += (double)zsh[i*4+2] * (double)e4.z;
                s3 += (double)zsh[i*4+3] * (double)e4.w;
            }
            const float qab  = (float)((s0 + s1) + (s2 + s3));  // sgemm proxy
            const float m2ab = __fmul_rn(-2.0f, qab);
            const float t1   = __fadd_rn(a2n, m2ab);
            const float dist = __fadd_rn(t1, b2[k]);
            if (dist < best) { best = dist; bi = k; }
        }
        bv[tid] = best; bix[tid] = bi;
        __syncthreads();
#pragma unroll
        for (int s = 128; s > 0; s >>= 1) {
            if (tid < s) {
                const float ov = bv[tid + s];
                const int   oi = bix[tid + s];
                if (ov < bv[tid] || (ov == bv[tid] && oi < bix[tid])) { bv[tid] = ov; bix[tid] = oi; }
            }
            __syncthreads();
        }
        if (tid == 0) {
            const int newbi = bix[0];
            const int oldbi = idx_out[n];
            if (newbi != oldbi) {
                idx_out[n] = newbi;
                out[IDX_OFF + n] = (float)newbi;
                atomicSub(&counts[oldbi], 1);
                atomicAdd(&counts[newbi], 1);
            }
        }
    }
}

// z_q gather via LDS tile (full emb lines once) + commit-loss partial.
// Grid 512 = one (b,h) tile (64 rows) per block.
__global__ __launch_bounds__(256)
void vq_quant(const float* __restrict__ z_e, const float* __restrict__ emb,
              const int* __restrict__ idx, float* __restrict__ out,
              float* __restrict__ loss_acc) {
    __shared__ float q[64][65];
    const int tid = threadIdx.x;
    const int tile = blockIdx.x;
    const int b = tile >> 6, h = tile & 63;
    {
        const int r = tid >> 2, qd = (tid & 3) * 16;
        const int code = idx[tile * 64 + r];
        const float4* er = (const float4*)(emb + code * DIMV + qd);
#pragma unroll
        for (int i = 0; i < 4; ++i) {
            const float4 e4 = er[i];
            q[r][qd + i*4 + 0] = e4.x;
            q[r][qd + i*4 + 1] = e4.y;
            q[r][qd + i*4 + 2] = e4.z;
            q[r][qd + i*4 + 3] = e4.w;
        }
    }
    __syncthreads();
    const int w = tid & 63, dq = tid >> 6;
    float dl = 0.f;
#pragma unroll
    for (int i = 0; i < 16; ++i) {
        const int d = dq * 16 + i;
        const int g = ((b * 64 + d) << 12) + (h << 6) + w;
        const float qq = q[w][d];
        const float zz = z_e[g];
        out[g] = qq;
        const float df = zz - qq;
        dl = fmaf(df, df, dl);
    }
    __shared__ float red[256];
    red[tid] = dl;
    __syncthreads();
#pragma unroll
    for (int s = 128; s > 0; s >>= 1) {
        if (tid < s) red[tid] += red[tid + s];
        __syncthreads();
    }
    if (tid == 0) atomicAdd(loss_acc, red[0]);
}

__global__ __launch_bounds__(256)
void vq_stats_kernel(const int* __restrict__ counts, const float* __restrict__ loss_acc,
                     float* __restrict__ out) {
    __shared__ float rent[256];
    __shared__ float ruse[256];
    float ent = 0.f, used = 0.f;
    for (int k = threadIdx.x; k < K_CODES; k += 256) {
        const int c = counts[k];
        if (c > 0) {
            const float avg = (float)c * (1.0f / 32768.0f);
            ent  += avg * logf(avg + 1e-10f);
            used += 1.0f;
        }
    }
    rent[threadIdx.x] = ent;
    ruse[threadIdx.x] = used;
    __syncthreads();
#pragma unroll
    for (int s = 128; s > 0; s >>= 1) {
        if (threadIdx.x < s) {
            rent[threadIdx.x] += rent[threadIdx.x + s];
            ruse[threadIdx.x] += ruse[threadIdx.x + s];
        }
        __syncthreads();
    }
    if (threadIdx.x == 0) {
        out[SCAL_OFF + 0] = 0.25f * loss_acc[0] * (1.0f / 2097152.0f);
        out[SCAL_OFF + 1] = expf(-rent[0]);
        out[SCAL_OFF + 2] = ruse[0] * (1.0f / 8192.0f);
    }
}

extern "C" void kernel_launch(void* const* d_in, const int* in_sizes, int n_in,
                              void* d_out, int out_size, void* d_ws, size_t ws_size,
                              hipStream_t stream) {
    const float* z_e = (const float*)d_in[0];
    const float* emb = (const float*)d_in[1];
    float* out = (float*)d_out;
    char*  ws  = (char*)d_ws;

    float* b2     = (float*)(ws + WS_B2);
    int*   idx    = (int*)(ws + WS_IDX);
    int*   counts = (int*)(ws + WS_CNT);
    float* loss   = (float*)(ws + WS_LOSS);
    int*   fcnt   = (int*)(ws + WS_FCNT);
    int*   flist  = (int*)(ws + WS_FLIST);
    float* a2     = (float*)(ws + WS_A2);
    short* efrag  = (short*)(ws + WS_EFRAG);
    short* zt_hi  = (short*)(ws + WS_ZHI);
    short* zt_lo  = (short*)(ws + WS_ZLO);
    float* p_b1v  = (float*)(ws + WS_P1V);
    float* p_b2v  = (float*)(ws + WS_P2V);
    int*   p_b1i  = (int*)(ws + WS_P1I);

    hipLaunchKernelGGL(vq_prep,        dim3(576),  dim3(256), 0, stream,
                       z_e, emb, a2, b2, zt_hi, zt_lo, efrag, counts);
    hipLaunchKernelGGL(vq_argmin_mfma, dim3(1024), dim3(256), 0, stream,
                       zt_hi, zt_lo, efrag, b2, p_b1v, p_b2v, p_b1i);
    hipLaunchKernelGGL(vq_merge,       dim3(128),  dim3(256), 0, stream,
                       p_b1v, p_b2v, p_b1i, idx, out, counts, fcnt, flist);
    hipLaunchKernelGGL(vq_refine_np,   dim3(512),  dim3(256), 0, stream,
                       z_e, emb, a2, b2, fcnt, flist, idx, out, counts);
    hipLaunchKernelGGL(vq_quant,       dim3(512),  dim3(256), 0, stream,
                       z_e, emb, idx, out, loss);
    hipLaunchKernelGGL(vq_stats_kernel, dim3(1),   dim3(256), 0, stream, counts, loss, out);
}

// Round 10
// 224.808 us; speedup vs baseline: 4.8466x; 1.3906x over previous
//
#include <hip/hip_runtime.h>

// VQ-VAE vector quantization, MI355X (gfx950).
// z_e: (8,64,64,64) f32 (B,D,H,W); emb: (8192,64) f32.
// N = 32768 rows (n = b*4096 + h*64 + w), D = 64, K = 8192.
// out (f32 concat): z_q[2097152] | indices[32768] | loss | perplexity | usage
//
// Fast pass: split-bf16 MFMA of score = b2 + z.(-2e) (e pre-scaled, frag-blocked,
// async global_load_lds staging, med3 top-2). Rows with fast gap < MARGIN get a
// numpy-fp32-emulated re-rank (round-3-verified numerics), parallelized as
// (row x K-quarter) jobs with LDS-tiled coalesced emb streaming.

#define K_CODES   8192
#define DIMV      64
#define IDX_OFF   2097152
#define SCAL_OFF  2129920
#define MARGIN    1e-4f   // flip bound ~4.4e-5; 2.3x headroom

// workspace layout (bytes)
#define WS_B2    0              // 8192 f32
#define WS_IDX   32768          // 32768 i32
#define WS_CNT   163840         // 8192 i32  (zeroed in prep)
#define WS_LOSS  196608         // 1 f32     (zeroed in prep)
#define WS_FCNT  196612         // 1 i32     (zeroed in prep)
#define WS_FLIST 196672         // 32768 i32
#define WS_A2    327744         // 32768 f32
#define WS_EFRAG 458816         // 128 chunks * 16 KB = 2 MB (frag-blocked -2e hi/lo)
#define WS_ZHI   2555968        // 32768*64 bf16 (4 MB)
#define WS_ZLO   6750272        // 4 MB
#define WS_P1V   10944576       // 4*32768 f32   (fast partials; reused by refine1)
#define WS_P2V   11468864       // 4*32768 f32
#define WS_P1I   11993152       // 4*32768 i32 (ends 12517440; reused by refine1)

typedef short s16x8  __attribute__((ext_vector_type(8)));
typedef float f32x4  __attribute__((ext_vector_type(4)));

__device__ __forceinline__ short bf16rne(float x) {
    unsigned u = __float_as_uint(x);
    unsigned r = (u + 0x7FFFu + ((u >> 16) & 1u)) >> 16;
    return (short)r;
}
__device__ __forceinline__ float bf16tof(short s) {
    return __uint_as_float(((unsigned)(unsigned short)s) << 16);
}

// async global->LDS copy, 16 B per lane (lds dest = wave-uniform base + lane*16)
__device__ __forceinline__ void gl_lds16(const char* g, char* l) {
    __builtin_amdgcn_global_load_lds(
        (const __attribute__((address_space(1))) unsigned int*)g,
        (__attribute__((address_space(3))) unsigned int*)l, 16, 0, 0);
}

// numpy pairwise-8 sum of squares (strictly rounded, no contraction)
__device__ __forceinline__ float pairwise8_sq(const float* __restrict__ x) {
    float r[8];
#pragma unroll
    for (int j = 0; j < 8; ++j) r[j] = __fmul_rn(x[j], x[j]);
#pragma unroll
    for (int i = 8; i < 64; i += 8)
#pragma unroll
        for (int j = 0; j < 8; ++j)
            r[j] = __fadd_rn(r[j], __fmul_rn(x[i + j], x[i + j]));
    const float s01 = __fadd_rn(r[0], r[1]);
    const float s23 = __fadd_rn(r[2], r[3]);
    const float s45 = __fadd_rn(r[4], r[5]);
    const float s67 = __fadd_rn(r[6], r[7]);
    return __fadd_rn(__fadd_rn(s01, s23), __fadd_rn(s45, s67));
}

// Fused prep: blocks [0,512) do z-prep; blocks [512,576) do emb-prep + zeroing.
__global__ __launch_bounds__(256)
void vq_prep(const float* __restrict__ z_e, const float* __restrict__ emb,
             float* __restrict__ a2, float* __restrict__ b2,
             short* __restrict__ zt_hi, short* __restrict__ zt_lo,
             short* __restrict__ efrag, int* __restrict__ zero_base) {
    const int blk = blockIdx.x;
    const int tid = threadIdx.x;
    if (blk < 512) {
        __shared__ float zs[64][65];
        const int b = blk >> 6, h = blk & 63;
        {
            const int w = tid & 63, dq = tid >> 6;
#pragma unroll
            for (int i = 0; i < 16; ++i) {
                const int dd = dq + i * 4;
                zs[w][dd] = z_e[((b * 64 + dd) << 12) + (h << 6) + w];
            }
        }
        __syncthreads();
        if (tid < 64) {
            float v[64];
#pragma unroll
            for (int d = 0; d < 64; ++d) v[d] = zs[tid][d];
            a2[blk * 64 + tid] = pairwise8_sq(v);
        }
        const int w = tid & 63, dq = tid >> 6;
        const int n = blk * 64 + w;
        s16x8 h8[2], l8[2];
#pragma unroll
        for (int i = 0; i < 16; ++i) {
            const float x = zs[w][dq * 16 + i];
            const short hh = bf16rne(x);
            ((short*)h8)[i] = hh;
            ((short*)l8)[i] = bf16rne(x - bf16tof(hh));
        }
        *(s16x8*)(zt_hi + n * DIMV + dq * 16)     = h8[0];
        *(s16x8*)(zt_hi + n * DIMV + dq * 16 + 8) = h8[1];
        *(s16x8*)(zt_lo + n * DIMV + dq * 16)     = l8[0];
        *(s16x8*)(zt_lo + n * DIMV + dq * 16 + 8) = l8[1];
    } else {
        const int zi = (blk - 512) * 256 + tid;
        if (zi < 8194) zero_base[zi] = 0;
        if (tid < 128) {
            const int k = (blk - 512) * 128 + tid;
            float v[64];
            const float4* row = (const float4*)(emb + k * DIMV);
#pragma unroll
            for (int i = 0; i < 16; ++i) {
                const float4 q = row[i];
                v[i*4+0] = q.x; v[i*4+1] = q.y; v[i*4+2] = q.z; v[i*4+3] = q.w;
            }
            b2[k] = pairwise8_sq(v);
            const int c = k >> 6, ct = (k >> 4) & 3, lcol = k & 15;
#pragma unroll
            for (int g = 0; g < 8; ++g) {
                s16x8 hv, lv;
#pragma unroll
                for (int j = 0; j < 8; ++j) {
                    const float x = -2.0f * v[g*8 + j];      // exact scale
                    const short hh = bf16rne(x);
                    hv[j] = hh;
                    lv[j] = bf16rne(x - bf16tof(hh));
                }
                const int f  = ct*4 + (g >> 2)*2;
                const int ln = (g & 3)*16 + lcol;
                *(s16x8*)(efrag + c*8192 + f*512     + ln*8) = hv;
                *(s16x8*)(efrag + c*8192 + (f+1)*512 + ln*8) = lv;
            }
        }
    }
}

// MFMA fast pass: async-LDS double buffer, med3 top-2, 4-way K-split.
__global__ __launch_bounds__(256, 4)
void vq_argmin_mfma(const short* __restrict__ zt_hi, const short* __restrict__ zt_lo,
                    const short* __restrict__ efrag, const float* __restrict__ b2,
                    float* __restrict__ p_b1v, float* __restrict__ p_b2v,
                    int* __restrict__ p_b1i) {
    __shared__ __align__(16) char lds[2][16384];
    const int tid  = threadIdx.x;
    const int lane = tid & 63;
    const int wid  = tid >> 6;
    const int blk  = blockIdx.x;
    const int quar = blk & 3;
    const int rgrp = blk >> 2;
    const int n0   = rgrp * 128 + wid * 32;
    const int lcol = lane & 15;
    const int kq   = lane >> 4;

    s16x8 a_h[2][2], a_l[2][2];
#pragma unroll
    for (int rt = 0; rt < 2; ++rt) {
        const short* zh = zt_hi + (size_t)(n0 + rt*16 + lcol) * DIMV + kq*8;
        const short* zl = zt_lo + (size_t)(n0 + rt*16 + lcol) * DIMV + kq*8;
        a_h[rt][0] = *(const s16x8*)(zh);
        a_h[rt][1] = *(const s16x8*)(zh + 32);
        a_l[rt][0] = *(const s16x8*)(zl);
        a_l[rt][1] = *(const s16x8*)(zl + 32);
    }

    float b1v[2][4], b2v[2][4]; int b1i[2][4];
#pragma unroll
    for (int rt = 0; rt < 2; ++rt)
#pragma unroll
        for (int r = 0; r < 4; ++r) { b1v[rt][r] = 3.4e38f; b2v[rt][r] = 3.4e38f; b1i[rt][r] = 0; }

    const int c0 = quar * 32;
    const char* gbase = (const char*)efrag;

    {
        const char* src = gbase + (size_t)c0 * 16384 + tid * 16;
        char* dst = &lds[0][tid * 16];
#pragma unroll
        for (int i = 0; i < 4; ++i) gl_lds16(src + i * 4096, dst + i * 4096);
    }

    for (int t = 0; t < 32; ++t) {
        __syncthreads();
        if (t < 31) {
            const char* src = gbase + (size_t)(c0 + t + 1) * 16384 + tid * 16;
            char* dst = &lds[(t + 1) & 1][tid * 16];
#pragma unroll
            for (int i = 0; i < 4; ++i) gl_lds16(src + i * 4096, dst + i * 4096);
        }
        const char* base = lds[t & 1];
        s16x8 B[16];
#pragma unroll
        for (int f = 0; f < 16; ++f)
            B[f] = *(const s16x8*)(base + f*1024 + lane*16);

        const int kt = (c0 + t) * 64;
        float b2f[4];
#pragma unroll
        for (int ct = 0; ct < 4; ++ct) b2f[ct] = b2[kt + ct*16 + lcol];

#pragma unroll
        for (int ct = 0; ct < 4; ++ct) {
            const int code = kt + ct*16 + lcol;
#pragma unroll
            for (int rt = 0; rt < 2; ++rt) {
                f32x4 acc = {b2f[ct], b2f[ct], b2f[ct], b2f[ct]};
                acc = __builtin_amdgcn_mfma_f32_16x16x32_bf16(a_h[rt][0], B[ct*4+0], acc, 0, 0, 0);
                acc = __builtin_amdgcn_mfma_f32_16x16x32_bf16(a_h[rt][1], B[ct*4+2], acc, 0, 0, 0);
                acc = __builtin_amdgcn_mfma_f32_16x16x32_bf16(a_l[rt][0], B[ct*4+0], acc, 0, 0, 0);
                acc = __builtin_amdgcn_mfma_f32_16x16x32_bf16(a_l[rt][1], B[ct*4+2], acc, 0, 0, 0);
                acc = __builtin_amdgcn_mfma_f32_16x16x32_bf16(a_h[rt][0], B[ct*4+1], acc, 0, 0, 0);
                acc = __builtin_amdgcn_mfma_f32_16x16x32_bf16(a_h[rt][1], B[ct*4+3], acc, 0, 0, 0);
#pragma unroll
                for (int r = 0; r < 4; ++r) {
                    const float v = acc[r];
                    b2v[rt][r] = __builtin_amdgcn_fmed3f(v, b1v[rt][r], b2v[rt][r]);
                    const bool lt = (v < b1v[rt][r]);
                    b1i[rt][r] = lt ? code : b1i[rt][r];
                    b1v[rt][r] = fminf(v, b1v[rt][r]);
                }
            }
        }
    }

#pragma unroll
    for (int m = 8; m >= 1; m >>= 1) {
#pragma unroll
        for (int rt = 0; rt < 2; ++rt)
#pragma unroll
            for (int r = 0; r < 4; ++r) {
                const float ov1 = __shfl_xor(b1v[rt][r], m);
                const int   oi1 = __shfl_xor(b1i[rt][r], m);
                const float ov2 = __shfl_xor(b2v[rt][r], m);
                const bool take = (ov1 < b1v[rt][r]) || (ov1 == b1v[rt][r] && oi1 < b1i[rt][r]);
                const float nb2 = take ? fminf(b1v[rt][r], ov2) : fminf(b2v[rt][r], ov1);
                if (take) { b1v[rt][r] = ov1; b1i[rt][r] = oi1; }
                b2v[rt][r] = nb2;
            }
    }
    if (lcol == 0) {
#pragma unroll
        for (int rt = 0; rt < 2; ++rt)
#pragma unroll
            for (int r = 0; r < 4; ++r) {
                const int n = n0 + rt*16 + kq*4 + r;
                p_b1v[quar * 32768 + n] = b1v[rt][r];
                p_b2v[quar * 32768 + n] = b2v[rt][r];
                p_b1i[quar * 32768 + n] = b1i[rt][r];
            }
    }
}

// merge 4 K-quarter partials -> idx + idx-as-float + counts + compacted flags
__global__ __launch_bounds__(256)
void vq_merge(const float* __restrict__ p_b1v, const float* __restrict__ p_b2v,
              const int* __restrict__ p_b1i, int* __restrict__ idx_out,
              float* __restrict__ out, int* __restrict__ counts,
              int* __restrict__ fcnt, int* __restrict__ flist) {
    const int n = blockIdx.x * 256 + threadIdx.x;
    float b1 = p_b1v[n], sec = p_b2v[n];
    int   bi = p_b1i[n];
#pragma unroll
    for (int q = 1; q < 4; ++q) {
        const float v = p_b1v[q * 32768 + n];
        const float s = p_b2v[q * 32768 + n];
        const int   i = p_b1i[q * 32768 + n];
        const bool take = (v < b1);                // earlier quarter wins ties
        sec = take ? fminf(b1, s) : fminf(sec, v);
        b1  = take ? v : b1;
        bi  = take ? i : bi;
    }
    idx_out[n] = bi;
    out[IDX_OFF + n] = (float)bi;
    atomicAdd(&counts[bi], 1);
    if (sec - b1 < MARGIN) {
        const int p = atomicAdd(fcnt, 1);
        flist[p] = n;
    }
}

// refine1: np-emulated distance argmin for flagged rows, job = (row, K-quarter).
// LDS-tiled coalesced emb; 2 threads/code (d-halves) with fp64 half-combine.
// Writes per-quarter best into the (now free) fast-pass partial buffers.
__global__ __launch_bounds__(256)
void vq_refine1(const float* __restrict__ z_e, const float* __restrict__ emb,
                const float* __restrict__ a2, const float* __restrict__ b2,
                const int* __restrict__ fcnt, const int* __restrict__ flist,
                float* __restrict__ pq_v, int* __restrict__ pq_i) {
    __shared__ float  es[128][65];   // pad 65: scalar reads/writes 2-way-free
    __shared__ float  zsh[64];
    __shared__ double pd[128];
    __shared__ float  bv[128];
    __shared__ int    bix[128];
    const int tid = threadIdx.x;
    const int cnt = *fcnt;
    const int njobs = cnt * 4;
    const int c  = tid & 127;        // code within tile
    const int hh = tid >> 7;         // d-half owner (0: d<32, 1: d>=32)
    const int dh = hh * 32;

    for (int j = blockIdx.x; j < njobs; j += gridDim.x) {
        const int it = j >> 2, q = j & 3;
        const int n  = flist[it];
        const int b = n >> 12, h = (n >> 6) & 63, w = n & 63;
        __syncthreads();             // protect zsh/es across job iterations
        if (tid < 64) zsh[tid] = z_e[(((b << 6) + tid) << 12) + (h << 6) + w];
        __syncthreads();

        float zreg[32];
#pragma unroll
        for (int i = 0; i < 32; ++i) zreg[i] = zsh[dh + i];
        const float a2n = a2[n];

        float best = 3.4e38f;
        int   bi   = 0;
        const int kbase = q * 2048;

        for (int t = 0; t < 16; ++t) {
            const int kt = kbase + t * 128;
            __syncthreads();         // es reuse barrier
            // stage 128 codes x 64 dims, coalesced f4 global loads
#pragma unroll
            for (int i = 0; i < 8; ++i) {
                const int g  = i * 256 + tid;          // f4 slot in tile
                const int cc = g >> 4, dd = (g & 15) * 4;
                const float4 v = *(const float4*)(emb + (size_t)(kt + cc) * DIMV + dd);
                es[cc][dd + 0] = v.x; es[cc][dd + 1] = v.y;
                es[cc][dd + 2] = v.z; es[cc][dd + 3] = v.w;
            }
            __syncthreads();

            double s0 = 0.0, s1 = 0.0, s2 = 0.0, s3 = 0.0;
#pragma unroll
            for (int i = 0; i < 32; i += 4) {
                s0 += (double)zreg[i + 0] * (double)es[c][dh + i + 0];
                s1 += (double)zreg[i + 1] * (double)es[c][dh + i + 1];
                s2 += (double)zreg[i + 2] * (double)es[c][dh + i + 2];
                s3 += (double)zreg[i + 3] * (double)es[c][dh + i + 3];
            }
            const double sh = (s0 + s1) + (s2 + s3);
            if (hh == 1) pd[c] = sh;
            __syncthreads();
            if (hh == 0) {
                const double full = sh + pd[c];
                const float qab  = (float)full;              // sgemm proxy
                const float m2ab = __fmul_rn(-2.0f, qab);
                const float t1   = __fadd_rn(a2n, m2ab);
                const float dist = __fadd_rn(t1, b2[kt + c]);
                if (dist < best) { best = dist; bi = kt + c; }  // per-thread k ascending
            }
        }

        // block-reduce 128 owner-threads (first-occurrence tie-break)
        if (hh == 0) { bv[c] = best; bix[c] = bi; }
        __syncthreads();
#pragma unroll
        for (int s = 64; s > 0; s >>= 1) {
            if (tid < s) {
                const float ov = bv[tid + s];
                const int   oi = bix[tid + s];
                if (ov < bv[tid] || (ov == bv[tid] && oi < bix[tid])) { bv[tid] = ov; bix[tid] = oi; }
            }
            __syncthreads();
        }
        if (tid == 0) { pq_v[q * 32768 + n] = bv[0]; pq_i[q * 32768 + n] = bix[0]; }
    }
}

// refine2: combine 4 np-quarters per flagged row; patch idx/out/counts.
__global__ __launch_bounds__(256)
void vq_refine2(const float* __restrict__ pq_v, const int* __restrict__ pq_i,
                const int* __restrict__ fcnt, const int* __restrict__ flist,
                int* __restrict__ idx_out, float* __restrict__ out,
                int* __restrict__ counts) {
    const int cnt = *fcnt;
    for (int i = blockIdx.x * 256 + threadIdx.x; i < cnt; i += gridDim.x * 256) {
        const int n = flist[i];
        float best = pq_v[n];
        int   bi   = pq_i[n];
#pragma unroll
        for (int q = 1; q < 4; ++q) {
            const float v = pq_v[q * 32768 + n];
            if (v < best) { best = v; bi = pq_i[q * 32768 + n]; }  // ascending q: tie keeps earlier
        }
        const int oldbi = idx_out[n];
        if (bi != oldbi) {
            idx_out[n] = bi;
            out[IDX_OFF + n] = (float)bi;
            atomicSub(&counts[oldbi], 1);
            atomicAdd(&counts[bi], 1);
        }
    }
}

// z_q gather via LDS tile + commit-loss partial. Grid 512 = one (b,h) tile.
__global__ __launch_bounds__(256)
void vq_quant(const float* __restrict__ z_e, const float* __restrict__ emb,
              const int* __restrict__ idx, float* __restrict__ out,
              float* __restrict__ loss_acc) {
    __shared__ float q[64][65];
    const int tid = threadIdx.x;
    const int tile = blockIdx.x;
    const int b = tile >> 6, h = tile & 63;
    {
        const int r = tid >> 2, qd = (tid & 3) * 16;
        const int code = idx[tile * 64 + r];
        const float4* er = (const float4*)(emb + code * DIMV + qd);
#pragma unroll
        for (int i = 0; i < 4; ++i) {
            const float4 e4 = er[i];
            q[r][qd + i*4 + 0] = e4.x;
            q[r][qd + i*4 + 1] = e4.y;
            q[r][qd + i*4 + 2] = e4.z;
            q[r][qd + i*4 + 3] = e4.w;
        }
    }
    __syncthreads();
    const int w = tid & 63, dq = tid >> 6;
    float dl = 0.f;
#pragma unroll
    for (int i = 0; i < 16; ++i) {
        const int d = dq * 16 + i;
        const int g = ((b * 64 + d) << 12) + (h << 6) + w;
        const float qq = q[w][d];
        const float zz = z_e[g];
        out[g] = qq;
        const float df = zz - qq;
        dl = fmaf(df, df, dl);
    }
    __shared__ float red[256];
    red[tid] = dl;
    __syncthreads();
#pragma unroll
    for (int s = 128; s > 0; s >>= 1) {
        if (tid < s) red[tid] += red[tid + s];
        __syncthreads();
    }
    if (tid == 0) atomicAdd(loss_acc, red[0]);
}

__global__ __launch_bounds__(256)
void vq_stats_kernel(const int* __restrict__ counts, const float* __restrict__ loss_acc,
                     float* __restrict__ out) {
    __shared__ float rent[256];
    __shared__ float ruse[256];
    float ent = 0.f, used = 0.f;
    for (int k = threadIdx.x; k < K_CODES; k += 256) {
        const int c = counts[k];
        if (c > 0) {
            const float avg = (float)c * (1.0f / 32768.0f);
            ent  += avg * logf(avg + 1e-10f);
            used += 1.0f;
        }
    }
    rent[threadIdx.x] = ent;
    ruse[threadIdx.x] = used;
    __syncthreads();
#pragma unroll
    for (int s = 128; s > 0; s >>= 1) {
        if (threadIdx.x < s) {
            rent[threadIdx.x] += rent[threadIdx.x + s];
            ruse[threadIdx.x] += ruse[threadIdx.x + s];
        }
        __syncthreads();
    }
    if (threadIdx.x == 0) {
        out[SCAL_OFF + 0] = 0.25f * loss_acc[0] * (1.0f / 2097152.0f);
        out[SCAL_OFF + 1] = expf(-rent[0]);
        out[SCAL_OFF + 2] = ruse[0] * (1.0f / 8192.0f);
    }
}

extern "C" void kernel_launch(void* const* d_in, const int* in_sizes, int n_in,
                              void* d_out, int out_size, void* d_ws, size_t ws_size,
                              hipStream_t stream) {
    const float* z_e = (const float*)d_in[0];
    const float* emb = (const float*)d_in[1];
    float* out = (float*)d_out;
    char*  ws  = (char*)d_ws;

    float* b2     = (float*)(ws + WS_B2);
    int*   idx    = (int*)(ws + WS_IDX);
    int*   counts = (int*)(ws + WS_CNT);
    float* loss   = (float*)(ws + WS_LOSS);
    int*   fcnt   = (int*)(ws + WS_FCNT);
    int*   flist  = (int*)(ws + WS_FLIST);
    float* a2     = (float*)(ws + WS_A2);
    short* efrag  = (short*)(ws + WS_EFRAG);
    short* zt_hi  = (short*)(ws + WS_ZHI);
    short* zt_lo  = (short*)(ws + WS_ZLO);
    float* p_b1v  = (float*)(ws + WS_P1V);
    float* p_b2v  = (float*)(ws + WS_P2V);
    int*   p_b1i  = (int*)(ws + WS_P1I);

    hipLaunchKernelGGL(vq_prep,        dim3(576),  dim3(256), 0, stream,
                       z_e, emb, a2, b2, zt_hi, zt_lo, efrag, counts);
    hipLaunchKernelGGL(vq_argmin_mfma, dim3(1024), dim3(256), 0, stream,
                       zt_hi, zt_lo, efrag, b2, p_b1v, p_b2v, p_b1i);
    hipLaunchKernelGGL(vq_merge,       dim3(128),  dim3(256), 0, stream,
                       p_b1v, p_b2v, p_b1i, idx, out, counts, fcnt, flist);
    // refine reuses p_b1v/p_b1i as per-quarter np partials (fast pass done)
    hipLaunchKernelGGL(vq_refine1,     dim3(1024), dim3(256), 0, stream,
                       z_e, emb, a2, b2, fcnt, flist, p_b1v, p_b1i);
    hipLaunchKernelGGL(vq_refine2,     dim3(64),   dim3(256), 0, stream,
                       p_b1v, p_b1i, fcnt, flist, idx, out, counts);
    hipLaunchKernelGGL(vq_quant,       dim3(512),  dim3(256), 0, stream,
                       z_e, emb, idx, out, loss);
    hipLaunchKernelGGL(vq_stats_kernel, dim3(1),   dim3(256), 0, stream, counts, loss, out);
}